// Round 5
// baseline (369.292 us; speedup 1.0000x reference)
//
#include <hip/hip_runtime.h>

#define B_ 1024
#define M_ 64
#define N_ 8192
#define NSG 16   // k-splits for k_G  (chunk 1024 of K=16384)
#define NS3 8    // n-slabs for k_H23 (1024 cols each)

typedef __attribute__((ext_vector_type(8))) short bf16x8;
typedef __attribute__((ext_vector_type(4))) float f32x4;

__device__ inline unsigned short f2b(float f) {
    union { float f; unsigned u; } v; v.f = f;
    unsigned r = v.u + 0x7FFFu + ((v.u >> 16) & 1u);
    return (unsigned short)(r >> 16);
}
__device__ inline unsigned rne2(float lo, float hi) {
    union { float f; unsigned u; } a, b; a.f = lo; b.f = hi;
    unsigned x = (a.u + 0x7FFFu + ((a.u >> 16) & 1u)) >> 16;
    unsigned y = (b.u + 0x7FFFu + ((b.u >> 16) & 1u)) >> 16;
    return x | (y << 16);
}
__device__ inline float b2f(unsigned short s) {
    union { unsigned u; float f; } v; v.u = ((unsigned)s) << 16; return v.f;
}
// readlane with uniform (dynamic) lane index -> SALU broadcast (r8-proven)
__device__ inline float rl(float v, int l) {
    return __builtin_bit_cast(float, __builtin_amdgcn_readlane(__builtin_bit_cast(int, v), l));
}

// ---------------------------------------------------------------------------
// k_cvtgj: fp32 -> bf16 stream for rn (blocks 1..8192) + panel-4 blocked
// complex Gauss-Jordan inverse of S -> Wt (block 0).
//
// WHY HERE (r3/r4 lesson): hiding the GJ under the k_Ginv GEMM fails —
// GJ-under-GEMM-load ran ~52-67us (vs ~9-15us solo estimate) across two
// structures, with setprio. The GEMM's 16 waves/CU of MFMA+addressing starve
// the GJ's latency-bound chain and priority doesn't recover it. cvt is pure
// streaming: its waves sleep on vmcnt, VALU issue on CU0 is ~free, so the GJ
// runs at ~solo rate in cvt's ~15us shadow. GJ is block 0 (NOT last): with
// 8193 blocks >> resident capacity, a last-block GJ would start only after
// most of cvt drained (r2 straggler lesson); block 0 is in the first dispatch
// round. Requires launch order: k_Sbuild BEFORE k_cvtgj (S ready).
__global__ __launch_bounds__(256) void k_cvtgj(const float* src, unsigned short* dst,
                                               const float* S, float* Wt) {
    int t = threadIdx.x;
    int lane = t & 63;
    if (blockIdx.x == 0) {
        // ---------------- panel-4 blocked inversion (r4-verified) ----------
        __builtin_amdgcn_s_setprio(1);
        __shared__ float2 Tp[2][4][64];   // [parity][panel col j][row]
        int g = t >> 6;
        float mx0,my0,mx1,my1,mx2,my2,mx3,my3,mx4,my4,mx5,my5,mx6,my6,mx7,my7;
        float mx8,my8,mx9,my9,mx10,my10,mx11,my11,mx12,my12,mx13,my13,mx14,my14,mx15,my15;
        // col mapping: J=4q+j -> c = 16q + 4g + j
#define GJ_INIT(J) { int c = 16 * ((J) >> 2) + 4 * g + ((J) & 3);            \
    float2 v = ((const float2*)S)[(size_t)lane * 64 + c];                    \
    mx##J = v.x; my##J = v.y; }
        GJ_INIT(0) GJ_INIT(1) GJ_INIT(2) GJ_INIT(3) GJ_INIT(4) GJ_INIT(5) GJ_INIT(6) GJ_INIT(7)
        GJ_INIT(8) GJ_INIT(9) GJ_INIT(10) GJ_INIT(11) GJ_INIT(12) GJ_INIT(13) GJ_INIT(14) GJ_INIT(15)
#undef GJ_INIT

// one in-register pivot on own panel: pivot col JA (k=4p+jj), update JB0..2 + JA
#define PIV(JA, JB0, JB1, JB2, jj) {                                         \
    int k = p4 + (jj);                                                       \
    float px = rl(mx##JA, k), py = rl(my##JA, k);                            \
    float d = px * px + py * py;                                             \
    float id = 1.0f / d;                                                     \
    float pix = px * id, piy = -py * id;                                     \
    bool isk = (lane == k);                                                  \
    float a   = isk ? 0.f : 1.f;                                             \
    float fpx = isk ? -pix : (mx##JA * pix - my##JA * piy);                  \
    float fpy = isk ? -piy : (mx##JA * piy + my##JA * pix);                  \
    { float sx = rl(mx##JB0, k), sy = rl(my##JB0, k);                        \
      float nx = a * mx##JB0 - (fpx * sx - fpy * sy);                        \
      float ny = a * my##JB0 - (fpx * sy + fpy * sx);                        \
      mx##JB0 = nx; my##JB0 = ny; }                                          \
    { float sx = rl(mx##JB1, k), sy = rl(my##JB1, k);                        \
      float nx = a * mx##JB1 - (fpx * sx - fpy * sy);                        \
      float ny = a * my##JB1 - (fpx * sy + fpy * sx);                        \
      mx##JB1 = nx; my##JB1 = ny; }                                          \
    { float sx = rl(mx##JB2, k), sy = rl(my##JB2, k);                        \
      float nx = a * mx##JB2 - (fpx * sx - fpy * sy);                        \
      float ny = a * my##JB2 - (fpx * sy + fpy * sx);                        \
      mx##JB2 = nx; my##JB2 = ny; }                                          \
    mx##JA = -fpx; my##JA = -fpy; }

#define FACT4(J0, J1, J2, J3) {                                              \
    PIV(J0, J1, J2, J3, 0) PIV(J1, J0, J2, J3, 1)                            \
    PIV(J2, J0, J1, J3, 2) PIV(J3, J0, J1, J2, 3)                            \
    Tp[buf][0][lane] = make_float2(mx##J0, my##J0);                          \
    Tp[buf][1][lane] = make_float2(mx##J1, my##J1);                          \
    Tp[buf][2][lane] = make_float2(mx##J2, my##J2);                          \
    Tp[buf][3][lane] = make_float2(mx##J3, my##J3); }

        for (int p = 0; p < 16; ++p) {
            const int buf = p & 1;
            const int p4  = p * 4;
            const int q   = p >> 2;
            const bool own = (g == (p & 3));
            if (own) {
                switch (q) {
                    case 0:  FACT4(0, 1, 2, 3)     break;
                    case 1:  FACT4(4, 5, 6, 7)     break;
                    case 2:  FACT4(8, 9, 10, 11)   break;
                    default: FACT4(12, 13, 14, 15) break;
                }
            }
            __syncthreads();
            float2 t0 = Tp[buf][0][lane];
            float2 t1 = Tp[buf][1][lane];
            float2 t2 = Tp[buf][2][lane];
            float2 t3 = Tp[buf][3][lane];
            float msk = ((lane >> 2) == p) ? 0.f : 1.f;
            int skipq = own ? q : -1;
// closed-form rank-4 update: col <- msk*col + Tp * s_orig (s read before write)
#define TRAIL(J) if (((J) >> 2) != skipq) {                                  \
    float s0x = rl(mx##J, p4),     s0y = rl(my##J, p4);                      \
    float s1x = rl(mx##J, p4 + 1), s1y = rl(my##J, p4 + 1);                  \
    float s2x = rl(mx##J, p4 + 2), s2y = rl(my##J, p4 + 2);                  \
    float s3x = rl(mx##J, p4 + 3), s3y = rl(my##J, p4 + 3);                  \
    float ax = msk * mx##J, ay = msk * my##J;                                \
    ax += t0.x * s0x - t0.y * s0y; ay += t0.x * s0y + t0.y * s0x;            \
    ax += t1.x * s1x - t1.y * s1y; ay += t1.x * s1y + t1.y * s1x;            \
    ax += t2.x * s2x - t2.y * s2y; ay += t2.x * s2y + t2.y * s2x;            \
    ax += t3.x * s3x - t3.y * s3y; ay += t3.x * s3y + t3.y * s3x;            \
    mx##J = ax; my##J = ay; }
            TRAIL(0)  TRAIL(1)  TRAIL(2)  TRAIL(3)
            TRAIL(4)  TRAIL(5)  TRAIL(6)  TRAIL(7)
            TRAIL(8)  TRAIL(9)  TRAIL(10) TRAIL(11)
            TRAIL(12) TRAIL(13) TRAIL(14) TRAIL(15)
#undef TRAIL
        }
#undef FACT4
#undef PIV
#define GJ_OUT(J) { int c = 16 * ((J) >> 2) + 4 * g + ((J) & 3);             \
    ((float2*)Wt)[(size_t)c * 64 + lane] = make_float2(mx##J, my##J); }
        GJ_OUT(0) GJ_OUT(1) GJ_OUT(2) GJ_OUT(3) GJ_OUT(4) GJ_OUT(5) GJ_OUT(6) GJ_OUT(7)
        GJ_OUT(8) GJ_OUT(9) GJ_OUT(10) GJ_OUT(11) GJ_OUT(12) GJ_OUT(13) GJ_OUT(14) GJ_OUT(15)
#undef GJ_OUT
        __builtin_amdgcn_s_setprio(0);
        return;
    }
    // ---------------- cvt path (blocks 1..8192) ----------------
    size_t i = ((size_t)(blockIdx.x - 1) * 256 + t) * 8;
    float4 f0 = *(const float4*)(src + i);
    float4 f1 = *(const float4*)(src + i + 4);
    union { bf16x8 v; unsigned u[4]; } r;
    r.u[0] = rne2(f0.x, f0.y); r.u[1] = rne2(f0.z, f0.w);
    r.u[2] = rne2(f1.x, f1.y); r.u[3] = rne2(f1.z, f1.w);
    *(bf16x8*)(dst + i) = r.v;
}

// ---------------------------------------------------------------------------
// Fused A-prep: one pass over A produces Abf (bf16 copy), ATb (transpose,
// [n][c*64+m]), WgT ([o][k]: o<64 -> [Ar|-Ai], o>=64 -> [Ai|Ar]).
__global__ __launch_bounds__(256) void k_prep(const float* A, unsigned short* Abf,
                                              unsigned short* WgT, unsigned short* ATb) {
    __shared__ float tile[128][65];
    int n0 = blockIdx.x * 64;
    int t = threadIdx.x;
    int nl = t % 64, r0 = t / 64;
#pragma unroll
    for (int it = 0; it < 32; ++it) {
        int row = r0 + it * 4;                       // row = c*64+m
        tile[row][nl] = A[(size_t)row * N_ + n0 + nl];
    }
    __syncthreads();
    // Abf + WgT (row-major reads of tile)
#pragma unroll
    for (int it = 0; it < 32; ++it) {
        int row = r0 + it * 4;
        float v = tile[row][nl];
        unsigned short bv = f2b(v);
        Abf[(size_t)row * N_ + n0 + nl] = bv;
        if (row < 64) {   // Ar[m]
            WgT[(size_t)row * 16384 + n0 + nl] = bv;                 // o=m,    k-low
            WgT[(size_t)(64 + row) * 16384 + 8192 + n0 + nl] = bv;   // o=64+m, k-high
        } else {          // Ai[m], m=row-64
            int m = row - 64;
            WgT[(size_t)m * 16384 + 8192 + n0 + nl] = f2b(-v);       // o=m,    k-high
            WgT[(size_t)(64 + m) * 16384 + n0 + nl] = bv;            // o=64+m, k-low
        }
    }
    // ATb (transposed reads)
    int o = t % 128, nn0 = t / 128;
#pragma unroll
    for (int it = 0; it < 32; ++it) {
        int nn = nn0 + it * 2;
        ATb[(size_t)(n0 + nn) * 128 + o] = f2b(tile[o][nn]);
    }
}

// ---------------------------------------------------------------------------
// S = I/(rho+1e-12) + A A^H  (complex 64x64, Hermitian). fp32.
__global__ __launch_bounds__(256) void k_Sbuild(const float* A, const float* lr,
                                                float* S, float* AAHT) {
    __shared__ float redS[8];
    int bid = blockIdx.x;
    int i = 0, rem = bid;
    while (rem >= 64 - i) { rem -= 64 - i; ++i; }
    int j = i + rem;                       // i <= j
    int t = threadIdx.x;
    const float* Ar = A;
    const float* Ai = A + (size_t)M_ * N_;
    const float* ari = Ar + (size_t)i * N_;
    const float* aii = Ai + (size_t)i * N_;
    const float* arj = Ar + (size_t)j * N_;
    const float* aij = Ai + (size_t)j * N_;
    float aR = 0.f, aI = 0.f;
#pragma unroll
    for (int it = 0; it < 8; ++it) {
        int n = it * 1024 + t * 4;
        float4 xr = *(const float4*)(ari + n);
        float4 xi = *(const float4*)(aii + n);
        float4 br = *(const float4*)(arj + n);
        float4 bi = *(const float4*)(aij + n);
        aR += xr.x * br.x + xi.x * bi.x + xr.y * br.y + xi.y * bi.y
            + xr.z * br.z + xi.z * bi.z + xr.w * br.w + xi.w * bi.w;
        aI += xi.x * br.x - xr.x * bi.x + xi.y * br.y - xr.y * bi.y
            + xi.z * br.z - xr.z * bi.z + xi.w * br.w - xr.w * bi.w;
    }
    for (int off = 32; off > 0; off >>= 1) {
        aR += __shfl_down(aR, off, 64);
        aI += __shfl_down(aI, off, 64);
    }
    int lane = t & 63, w = t >> 6;
    if (lane == 0) { redS[w * 2] = aR; redS[w * 2 + 1] = aI; }
    __syncthreads();
    if (t == 0) {
        float R = redS[0] + redS[2] + redS[4] + redS[6];
        float I = redS[1] + redS[3] + redS[5] + redS[7];
        float inv_rho = 1.0f / (expf(lr[0]) + 1e-12f);
        float diag = (i == j) ? inv_rho : 0.f;
        S[((size_t)i * 64 + j) * 2 + 0] = R + diag;
        S[((size_t)i * 64 + j) * 2 + 1] = I;
        AAHT[((size_t)j * 64 + i) * 2 + 0] = R;
        AAHT[((size_t)j * 64 + i) * 2 + 1] = I;
        if (i != j) {
            S[((size_t)j * 64 + i) * 2 + 0] = R;
            S[((size_t)j * 64 + i) * 2 + 1] = -I;
            AAHT[((size_t)i * 64 + j) * 2 + 0] = R;
            AAHT[((size_t)i * 64 + j) * 2 + 1] = -I;
        }
    }
}

// ---------------------------------------------------------------------------
// k_Ginv: now a PURE GEMM (GJ moved to k_cvtgj block 0 — r3/r4 showed the GJ
// can't hide under this GEMM's load).  grid = 1024.
//   Gpart[split][b][o] = sum_k rnb[b][k] * WgT[o][k] (MFMA)
__global__ __launch_bounds__(256, 2) void k_Ginv(const unsigned short* rnb,
                                                 const unsigned short* WgT,
                                                 float* Gpart) {
    int t = threadIdx.x;
    int lane = t & 63;
    int bx = blockIdx.x;
    int w = t >> 6;
    int l15 = lane & 15;
    int q8 = (lane >> 4) * 8;
    int split = bx & 15;
    int b0 = (bx >> 4) * 16;
    int k0 = split * 1024;
    f32x4 a00 = {}, a01 = {};
    const unsigned short* x0 = rnb + (size_t)(b0 + l15) * 16384 + k0 + q8;
    const unsigned short* w0 = WgT + (size_t)(w * 32 + l15) * 16384 + k0 + q8;
    const unsigned short* w1 = w0 + (size_t)16 * 16384;
#pragma unroll 8
    for (int ks = 0; ks < 32; ++ks) {
        int kk = ks * 32;
        bf16x8 af0 = *(const bf16x8*)(x0 + kk);
        bf16x8 bf0 = *(const bf16x8*)(w0 + kk);
        bf16x8 bf1 = *(const bf16x8*)(w1 + kk);
        a00 = __builtin_amdgcn_mfma_f32_16x16x32_bf16(af0, bf0, a00, 0, 0, 0);
        a01 = __builtin_amdgcn_mfma_f32_16x16x32_bf16(af0, bf1, a01, 0, 0, 0);
    }
    int row = (lane >> 4) * 4;
    size_t base = (size_t)split * (B_ * 128);
    float* g = Gpart + base + (size_t)(b0 + row) * 128 + w * 32 + l15;
#pragma unroll
    for (int r = 0; r < 4; ++r) {
        g[(size_t)r * 128] = a00[r];
        g[(size_t)r * 128 + 16] = a01[r];
    }
}

// ---------------------------------------------------------------------------
// per-step small: Ab = sum(Gpart) + rho*AAH*(z-u);  qb = bf16(rho*(z-u) - S^-1*Ab)
__global__ __launch_bounds__(256) void k_small12(const float* Gpart, const float* AAHT,
                                                 const float* Wt, const float* zin,
                                                 const float* uin, const float* lr,
                                                 unsigned short* qb) {
    __shared__ float2 AbS[4][64];
    int t = threadIdx.x;
    int m = t & 63;
    int w = __builtin_amdgcn_readfirstlane(t >> 6);
    int b = blockIdx.x * 4 + w;
    float rho = expf(lr[0]);
    float abR = 0.f, abI = 0.f;
    for (int k = 0; k < 64; ++k) {
        float wr = zin[(b * 2 + 0) * 64 + k] - uin[(b * 2 + 0) * 64 + k];
        float wi = zin[(b * 2 + 1) * 64 + k] - uin[(b * 2 + 1) * 64 + k];
        float2 h = *(const float2*)(AAHT + ((size_t)k * 64 + m) * 2);  // AAH[m][k]
        abR += wr * h.x - wi * h.y;
        abI += wi * h.x + wr * h.y;
    }
    float gR = 0.f, gI = 0.f;
#pragma unroll
    for (int s = 0; s < NSG; ++s) {
        gR += Gpart[(size_t)s * 131072 + (size_t)b * 128 + m];
        gI += Gpart[(size_t)s * 131072 + (size_t)b * 128 + 64 + m];
    }
    abR = gR + rho * abR;
    abI = gI + rho * abI;
    AbS[w][m] = make_float2(abR, abI);
    __syncthreads();
    float tR = 0.f, tI = 0.f;
    for (int k = 0; k < 64; ++k) {
        float2 Wv = *(const float2*)(Wt + ((size_t)k * 64 + m) * 2);   // W[m][k]
        float2 ab = AbS[w][k];
        tR += ab.x * Wv.x - ab.y * Wv.y;
        tI += ab.y * Wv.x + ab.x * Wv.y;
    }
    float wr_m = zin[(b * 2 + 0) * 64 + m] - uin[(b * 2 + 0) * 64 + m];
    float wi_m = zin[(b * 2 + 1) * 64 + m] - uin[(b * 2 + 1) * 64 + m];
    qb[(size_t)b * 128 + m] = f2b(rho * wr_m - tR);
    qb[(size_t)b * 128 + 64 + m] = f2b(rho * wi_m - tI);
}

// ---------------------------------------------------------------------------
// k_H23: fused x-update + Ax partials; last step also writes fp32 out (real)
// and zeros the imag rows (absorbs k_zero_imag). rn read as bf16 (rnb).
__global__ __launch_bounds__(256, 3) void k_H23(const unsigned short* qb, const unsigned short* ATb,
                                                const unsigned short* rnb, const unsigned short* Abf,
                                                float* out, float* Axpart, int last) {
    __shared__ __align__(16) char lds_buf[4 * 8448];
    int t = threadIdx.x;
    int lane = t & 63;
    int w = t >> 6;
    int l15 = lane & 15;
    int q8 = (lane >> 4) * 8;
    int row = (lane >> 4) * 4;
    int slab = blockIdx.x;
    int b0 = blockIdx.y * 16;
    int n0 = slab * 1024 + w * 256;
    short* xs = (short*)(lds_buf + w * 8448);      // [16][264] bf16 (row stride 528B)
    float* rs = (float*)(lds_buf + w * 8448);      // [16][132] fp32 alias (same wave only)

    // ---- phase 1
    bf16x8 a[4];
    const unsigned short* qrow = qb + (size_t)(b0 + l15) * 128 + q8;
#pragma unroll
    for (int ks = 0; ks < 4; ++ks) a[ks] = *(const bf16x8*)(qrow + ks * 32);
#pragma unroll 2
    for (int nt = 0; nt < 16; ++nt) {
        f32x4 acc = {};
        const unsigned short* bbase = ATb + (size_t)(n0 + nt * 16 + l15) * 128 + q8;
#pragma unroll
        for (int ks = 0; ks < 4; ++ks) {
            bf16x8 bf = *(const bf16x8*)(bbase + ks * 32);
            acc = __builtin_amdgcn_mfma_f32_16x16x32_bf16(a[ks], bf, acc, 0, 0, 0);
        }
        int ncol = n0 + nt * 16 + l15;
        int nloc = nt * 16 + l15;
#pragma unroll
        for (int r = 0; r < 4; ++r) {
            size_t ridx = (size_t)(b0 + row + r) * 16384 + ncol;   // real row of rn/out
            float v = fmaxf(acc[r] + b2f(rnb[ridx]), 0.f);
            if (last) out[ridx] = v;
            xs[(row + r) * 264 + nloc] = (short)f2b(v);
        }
    }
    // ---- phase 2 (wave-private x-stage: lgkmcnt orders RAW)
    f32x4 acc8[8] = {};
#pragma unroll
    for (int ks = 0; ks < 8; ++ks) {
        bf16x8 xf = *(const bf16x8*)(xs + l15 * 264 + ks * 32 + q8);
#pragma unroll
        for (int ot = 0; ot < 8; ++ot) {
            const unsigned short* bp = Abf + (size_t)(ot * 16 + l15) * 8192 + n0 + ks * 32 + q8;
            acc8[ot] = __builtin_amdgcn_mfma_f32_16x16x32_bf16(xf, *(const bf16x8*)bp, acc8[ot], 0, 0, 0);
        }
    }
    // ---- phase 3
    __syncthreads();
#pragma unroll
    for (int ot = 0; ot < 8; ++ot)
#pragma unroll
        for (int r = 0; r < 4; ++r)
            rs[(row + r) * 132 + ot * 16 + l15] = acc8[ot][r];
    __syncthreads();
#pragma unroll
    for (int e = t; e < 2048; e += 256) {
        int b = e >> 7, o = e & 127;
        float sAx = 0.f;
#pragma unroll
        for (int ww = 0; ww < 4; ++ww)
            sAx += ((const float*)(lds_buf + ww * 8448))[b * 132 + o];
        Axpart[(size_t)slab * 131072 + (size_t)(b0 + b) * 128 + o] = sAx;
    }
    // ---- zero imag rows of out (absorbed k_zero_imag)
    if (last) {
        float4 z4 = make_float4(0.f, 0.f, 0.f, 0.f);
        for (int e = t; e < 4096; e += 256) {
            int bb = e >> 8, nq = e & 255;
            *(float4*)(out + ((size_t)(b0 + bb) * 2 + 1) * N_ + slab * 1024 + nq * 4) = z4;
        }
    }
}

// ---------------------------------------------------------------------------
// per-step epilogue
__global__ __launch_bounds__(128) void k_small3(const float* Axpart, const float* uin,
                                                const float* y, const float* le,
                                                float* z, float* u, float* uout, int last) {
    __shared__ float red[2];
    int b = blockIdx.x, t = threadIdx.x;
    size_t idx = (size_t)b * 128 + t;
    float ax = 0.f;
#pragma unroll
    for (int s = 0; s < NS3; ++s) ax += Axpart[(size_t)s * 131072 + idx];
    float uo = uin[idx], yv = y[idx];
    float v = ax + uo - yv;
    float sq = v * v;
    for (int off = 32; off > 0; off >>= 1) sq += __shfl_down(sq, off, 64);
    if ((t & 63) == 0) red[t >> 6] = sq;
    __syncthreads();
    float tot = red[0] + red[1];
    float eps = expf(le[0]);
    float scale = fminf(1.f, eps / (sqrtf(tot) + 1e-12f));
    float zv = yv + v * scale;
    float un = uo + ax - zv;
    z[idx] = zv;
    u[idx] = un;
    if (last) uout[idx] = un;
}

// ---------------------------------------------------------------------------
extern "C" void kernel_launch(void* const* d_in, const int* in_sizes, int n_in,
                              void* d_out, int out_size, void* d_ws, size_t ws_size,
                              hipStream_t stream) {
    const float* rn  = (const float*)d_in[0];   // (B,2,N)
    const float* y   = (const float*)d_in[1];   // (B,2,M)
    const float* uin = (const float*)d_in[2];   // (B,2,M)
    const float* A   = (const float*)d_in[3];   // (2,M,N)
    const float* lr  = (const float*)d_in[4];   // log_rho
    const float* le  = (const float*)d_in[5];   // log_epsilon

    float* out = (float*)d_out;
    float* ws  = (float*)d_ws;

    float* Gpart  = ws;                             // 16*131072 = 2,097,152 f
    float* Axpart = Gpart + (size_t)NSG * 131072;   //  8*131072 = 1,048,576 f
    float* S      = Axpart + (size_t)NS3 * 131072;  // 8192
    float* AAHT   = S + 8192;                       // 8192
    float* Wt     = AAHT + 8192;                    // 8192
    float* z      = Wt + 8192;                      // 131072
    float* u      = z + 131072;                     // 131072
    unsigned short* qb  = (unsigned short*)(u + 131072);  // 131,072 us
    unsigned short* rnb = qb + 131072;              // B*2*N  = 16,777,216 us
    unsigned short* WgT = rnb + (size_t)B_ * 16384; // 128*16384 = 2,097,152 us
    unsigned short* Abf = WgT + 2097152;            // 2*64*8192 = 1,048,576 us
    unsigned short* ATb = Abf + 1048576;            // 8192*128  = 1,048,576 us
    float* uout = out + (size_t)B_ * 2 * N_;

    // order: Sbuild first (produces S), then cvt+GJ fused (GJ hides in cvt's
    // streaming shadow), then prep, then the pure GEMM.
    k_Sbuild<<<2080, 256, 0, stream>>>(A, lr, S, AAHT);
    k_cvtgj<<<8193, 256, 0, stream>>>(rn, rnb, S, Wt);
    k_prep<<<128, 256, 0, stream>>>(A, Abf, WgT, ATb);
    k_Ginv<<<1024, 256, 0, stream>>>(rnb, WgT, Gpart);

    for (int step = 0; step < 3; ++step) {
        const float* zp = (step == 0) ? y   : z;
        const float* up = (step == 0) ? uin : u;
        int last = (step == 2) ? 1 : 0;
        k_small12<<<256, 256, 0, stream>>>(Gpart, AAHT, Wt, zp, up, lr, qb);
        k_H23<<<dim3(NS3, 64), 256, 0, stream>>>(qb, ATb, rnb, Abf, out, Axpart, last);
        k_small3<<<B_, 128, 0, stream>>>(Axpart, up, y, le, z, u, uout, last);
    }
}

// Round 6
// 341.067 us; speedup vs baseline: 1.0828x; 1.0828x over previous
//
#include <hip/hip_runtime.h>

#define B_ 1024
#define M_ 64
#define N_ 8192
#define NSG 16   // k-splits for k_G  (chunk 1024 of K=16384)
#define NS3 8    // n-slabs for k_H23 (1024 cols each)

typedef __attribute__((ext_vector_type(8))) short bf16x8;
typedef __attribute__((ext_vector_type(4))) float f32x4;

__device__ inline unsigned short f2b(float f) {
    union { float f; unsigned u; } v; v.f = f;
    unsigned r = v.u + 0x7FFFu + ((v.u >> 16) & 1u);
    return (unsigned short)(r >> 16);
}
__device__ inline unsigned rne2(float lo, float hi) {
    union { float f; unsigned u; } a, b; a.f = lo; b.f = hi;
    unsigned x = (a.u + 0x7FFFu + ((a.u >> 16) & 1u)) >> 16;
    unsigned y = (b.u + 0x7FFFu + ((b.u >> 16) & 1u)) >> 16;
    return x | (y << 16);
}
__device__ inline float b2f(unsigned short s) {
    union { unsigned u; float f; } v; v.u = ((unsigned)s) << 16; return v.f;
}
// readlane with uniform (dynamic) lane index -> SALU broadcast (r8-proven)
__device__ inline float rl(float v, int l) {
    return __builtin_bit_cast(float, __builtin_amdgcn_readlane(__builtin_bit_cast(int, v), l));
}

// ---------------------------------------------------------------------------
// generic fp32 -> bf16 stream (8 elems/thread)
__global__ __launch_bounds__(256) void k_cvt(const float* src, unsigned short* dst) {
    size_t i = ((size_t)blockIdx.x * 256 + threadIdx.x) * 8;
    float4 f0 = *(const float4*)(src + i);
    float4 f1 = *(const float4*)(src + i + 4);
    union { bf16x8 v; unsigned u[4]; } r;
    r.u[0] = rne2(f0.x, f0.y); r.u[1] = rne2(f0.z, f0.w);
    r.u[2] = rne2(f1.x, f1.y); r.u[3] = rne2(f1.z, f1.w);
    *(bf16x8*)(dst + i) = r.v;
}

// ---------------------------------------------------------------------------
// Fused A-prep: one pass over A produces Abf (bf16 copy), ATb (transpose,
// [n][c*64+m]), WgT ([o][k]: o<64 -> [Ar|-Ai], o>=64 -> [Ai|Ar]).
__global__ __launch_bounds__(256) void k_prep(const float* A, unsigned short* Abf,
                                              unsigned short* WgT, unsigned short* ATb) {
    __shared__ float tile[128][65];
    int n0 = blockIdx.x * 64;
    int t = threadIdx.x;
    int nl = t % 64, r0 = t / 64;
#pragma unroll
    for (int it = 0; it < 32; ++it) {
        int row = r0 + it * 4;                       // row = c*64+m
        tile[row][nl] = A[(size_t)row * N_ + n0 + nl];
    }
    __syncthreads();
    // Abf + WgT (row-major reads of tile)
#pragma unroll
    for (int it = 0; it < 32; ++it) {
        int row = r0 + it * 4;
        float v = tile[row][nl];
        unsigned short bv = f2b(v);
        Abf[(size_t)row * N_ + n0 + nl] = bv;
        if (row < 64) {   // Ar[m]
            WgT[(size_t)row * 16384 + n0 + nl] = bv;                 // o=m,    k-low
            WgT[(size_t)(64 + row) * 16384 + 8192 + n0 + nl] = bv;   // o=64+m, k-high
        } else {          // Ai[m], m=row-64
            int m = row - 64;
            WgT[(size_t)m * 16384 + 8192 + n0 + nl] = f2b(-v);       // o=m,    k-high
            WgT[(size_t)(64 + m) * 16384 + n0 + nl] = bv;            // o=64+m, k-low
        }
    }
    // ATb (transposed reads)
    int o = t % 128, nn0 = t / 128;
#pragma unroll
    for (int it = 0; it < 32; ++it) {
        int nn = nn0 + it * 2;
        ATb[(size_t)(n0 + nn) * 128 + o] = f2b(tile[o][nn]);
    }
}

// ---------------------------------------------------------------------------
// S = I/(rho+1e-12) + A A^H  (complex 64x64, Hermitian). fp32.
__global__ __launch_bounds__(256) void k_Sbuild(const float* A, const float* lr,
                                                float* S, float* AAHT) {
    __shared__ float redS[8];
    int bid = blockIdx.x;
    int i = 0, rem = bid;
    while (rem >= 64 - i) { rem -= 64 - i; ++i; }
    int j = i + rem;                       // i <= j
    int t = threadIdx.x;
    const float* Ar = A;
    const float* Ai = A + (size_t)M_ * N_;
    const float* ari = Ar + (size_t)i * N_;
    const float* aii = Ai + (size_t)i * N_;
    const float* arj = Ar + (size_t)j * N_;
    const float* aij = Ai + (size_t)j * N_;
    float aR = 0.f, aI = 0.f;
#pragma unroll
    for (int it = 0; it < 8; ++it) {
        int n = it * 1024 + t * 4;
        float4 xr = *(const float4*)(ari + n);
        float4 xi = *(const float4*)(aii + n);
        float4 br = *(const float4*)(arj + n);
        float4 bi = *(const float4*)(aij + n);
        aR += xr.x * br.x + xi.x * bi.x + xr.y * br.y + xi.y * bi.y
            + xr.z * br.z + xi.z * bi.z + xr.w * br.w + xi.w * bi.w;
        aI += xi.x * br.x - xr.x * bi.x + xi.y * br.y - xr.y * bi.y
            + xi.z * br.z - xr.z * bi.z + xi.w * br.w - xr.w * bi.w;
    }
    for (int off = 32; off > 0; off >>= 1) {
        aR += __shfl_down(aR, off, 64);
        aI += __shfl_down(aI, off, 64);
    }
    int lane = t & 63, w = t >> 6;
    if (lane == 0) { redS[w * 2] = aR; redS[w * 2 + 1] = aI; }
    __syncthreads();
    if (t == 0) {
        float R = redS[0] + redS[2] + redS[4] + redS[6];
        float I = redS[1] + redS[3] + redS[5] + redS[7];
        float inv_rho = 1.0f / (expf(lr[0]) + 1e-12f);
        float diag = (i == j) ? inv_rho : 0.f;
        S[((size_t)i * 64 + j) * 2 + 0] = R + diag;
        S[((size_t)i * 64 + j) * 2 + 1] = I;
        AAHT[((size_t)j * 64 + i) * 2 + 0] = R;
        AAHT[((size_t)j * 64 + i) * 2 + 1] = I;
        if (i != j) {
            S[((size_t)j * 64 + i) * 2 + 0] = R;
            S[((size_t)j * 64 + i) * 2 + 1] = -I;
            AAHT[((size_t)i * 64 + j) * 2 + 0] = R;
            AAHT[((size_t)i * 64 + j) * 2 + 1] = -I;
        }
    }
}

// ---------------------------------------------------------------------------
// k_Ginv: heterogeneous fused kernel, grid = 1024 (r4-measured-best form).
//   block 0        : PANEL-4 blocked complex Gauss-Jordan inverse of S -> Wt,
//                    then falls through to its normal GEMM chunk (bx=0).
//   blocks 1..1023 : Gpart[split][b][o] = sum_k rnb[b][k] * WgT[o][k] (MFMA)
// (r5 lesson: relocating the GJ into the cvt kernel made the total WORSE —
// the GJ costs ~25-40us wherever it runs; r4's arrangement is the measured
// best. Keep it and attack the bigger fish instead.)
__global__ __launch_bounds__(256, 2) void k_Ginv(const unsigned short* rnb,
                                                 const unsigned short* WgT,
                                                 float* Gpart,
                                                 const float* S, float* Wt) {
    int t = threadIdx.x;
    int lane = t & 63;
    if (blockIdx.x == 0) {
        // ---------------- panel-4 blocked inversion ----------------
        __builtin_amdgcn_s_setprio(1);
        __shared__ float2 Tp[2][4][64];   // [parity][panel col j][row]
        int g = t >> 6;
        float mx0,my0,mx1,my1,mx2,my2,mx3,my3,mx4,my4,mx5,my5,mx6,my6,mx7,my7;
        float mx8,my8,mx9,my9,mx10,my10,mx11,my11,mx12,my12,mx13,my13,mx14,my14,mx15,my15;
        // col mapping: J=4q+j -> c = 16q + 4g + j
#define GJ_INIT(J) { int c = 16 * ((J) >> 2) + 4 * g + ((J) & 3);            \
    float2 v = ((const float2*)S)[(size_t)lane * 64 + c];                    \
    mx##J = v.x; my##J = v.y; }
        GJ_INIT(0) GJ_INIT(1) GJ_INIT(2) GJ_INIT(3) GJ_INIT(4) GJ_INIT(5) GJ_INIT(6) GJ_INIT(7)
        GJ_INIT(8) GJ_INIT(9) GJ_INIT(10) GJ_INIT(11) GJ_INIT(12) GJ_INIT(13) GJ_INIT(14) GJ_INIT(15)
#undef GJ_INIT

// one in-register pivot on own panel: pivot col JA (k=4p+jj), update JB0..2 + JA
#define PIV(JA, JB0, JB1, JB2, jj) {                                         \
    int k = p4 + (jj);                                                       \
    float px = rl(mx##JA, k), py = rl(my##JA, k);                            \
    float d = px * px + py * py;                                             \
    float id = 1.0f / d;                                                     \
    float pix = px * id, piy = -py * id;                                     \
    bool isk = (lane == k);                                                  \
    float a   = isk ? 0.f : 1.f;                                             \
    float fpx = isk ? -pix : (mx##JA * pix - my##JA * piy);                  \
    float fpy = isk ? -piy : (mx##JA * piy + my##JA * pix);                  \
    { float sx = rl(mx##JB0, k), sy = rl(my##JB0, k);                        \
      float nx = a * mx##JB0 - (fpx * sx - fpy * sy);                        \
      float ny = a * my##JB0 - (fpx * sy + fpy * sx);                        \
      mx##JB0 = nx; my##JB0 = ny; }                                          \
    { float sx = rl(mx##JB1, k), sy = rl(my##JB1, k);                        \
      float nx = a * mx##JB1 - (fpx * sx - fpy * sy);                        \
      float ny = a * my##JB1 - (fpx * sy + fpy * sx);                        \
      mx##JB1 = nx; my##JB1 = ny; }                                          \
    { float sx = rl(mx##JB2, k), sy = rl(my##JB2, k);                        \
      float nx = a * mx##JB2 - (fpx * sx - fpy * sy);                        \
      float ny = a * my##JB2 - (fpx * sy + fpy * sx);                        \
      mx##JB2 = nx; my##JB2 = ny; }                                          \
    mx##JA = -fpx; my##JA = -fpy; }

#define FACT4(J0, J1, J2, J3) {                                              \
    PIV(J0, J1, J2, J3, 0) PIV(J1, J0, J2, J3, 1)                            \
    PIV(J2, J0, J1, J3, 2) PIV(J3, J0, J1, J2, 3)                            \
    Tp[buf][0][lane] = make_float2(mx##J0, my##J0);                          \
    Tp[buf][1][lane] = make_float2(mx##J1, my##J1);                          \
    Tp[buf][2][lane] = make_float2(mx##J2, my##J2);                          \
    Tp[buf][3][lane] = make_float2(mx##J3, my##J3); }

        for (int p = 0; p < 16; ++p) {
            const int buf = p & 1;
            const int p4  = p * 4;
            const int q   = p >> 2;
            const bool own = (g == (p & 3));
            if (own) {
                switch (q) {
                    case 0:  FACT4(0, 1, 2, 3)     break;
                    case 1:  FACT4(4, 5, 6, 7)     break;
                    case 2:  FACT4(8, 9, 10, 11)   break;
                    default: FACT4(12, 13, 14, 15) break;
                }
            }
            __syncthreads();
            float2 t0 = Tp[buf][0][lane];
            float2 t1 = Tp[buf][1][lane];
            float2 t2 = Tp[buf][2][lane];
            float2 t3 = Tp[buf][3][lane];
            float msk = ((lane >> 2) == p) ? 0.f : 1.f;
            int skipq = own ? q : -1;
// closed-form rank-4 update: col <- msk*col + Tp * s_orig (s read before write)
#define TRAIL(J) if (((J) >> 2) != skipq) {                                  \
    float s0x = rl(mx##J, p4),     s0y = rl(my##J, p4);                      \
    float s1x = rl(mx##J, p4 + 1), s1y = rl(my##J, p4 + 1);                  \
    float s2x = rl(mx##J, p4 + 2), s2y = rl(my##J, p4 + 2);                  \
    float s3x = rl(mx##J, p4 + 3), s3y = rl(my##J, p4 + 3);                  \
    float ax = msk * mx##J, ay = msk * my##J;                                \
    ax += t0.x * s0x - t0.y * s0y; ay += t0.x * s0y + t0.y * s0x;            \
    ax += t1.x * s1x - t1.y * s1y; ay += t1.x * s1y + t1.y * s1x;            \
    ax += t2.x * s2x - t2.y * s2y; ay += t2.x * s2y + t2.y * s2x;            \
    ax += t3.x * s3x - t3.y * s3y; ay += t3.x * s3y + t3.y * s3x;            \
    mx##J = ax; my##J = ay; }
            TRAIL(0)  TRAIL(1)  TRAIL(2)  TRAIL(3)
            TRAIL(4)  TRAIL(5)  TRAIL(6)  TRAIL(7)
            TRAIL(8)  TRAIL(9)  TRAIL(10) TRAIL(11)
            TRAIL(12) TRAIL(13) TRAIL(14) TRAIL(15)
#undef TRAIL
        }
#undef FACT4
#undef PIV
#define GJ_OUT(J) { int c = 16 * ((J) >> 2) + 4 * g + ((J) & 3);             \
    ((float2*)Wt)[(size_t)c * 64 + lane] = make_float2(mx##J, my##J); }
        GJ_OUT(0) GJ_OUT(1) GJ_OUT(2) GJ_OUT(3) GJ_OUT(4) GJ_OUT(5) GJ_OUT(6) GJ_OUT(7)
        GJ_OUT(8) GJ_OUT(9) GJ_OUT(10) GJ_OUT(11) GJ_OUT(12) GJ_OUT(13) GJ_OUT(14) GJ_OUT(15)
#undef GJ_OUT
        __builtin_amdgcn_s_setprio(0);
        // fall through: block 0 also runs its GEMM chunk (bx = 0)
    }
    // ---------------- GEMM path (k_G) ----------------
    int bx = blockIdx.x;
    int w = t >> 6;
    int l15 = lane & 15;
    int q8 = (lane >> 4) * 8;
    int split = bx & 15;
    int b0 = (bx >> 4) * 16;
    int k0 = split * 1024;
    f32x4 a00 = {}, a01 = {};
    const unsigned short* x0 = rnb + (size_t)(b0 + l15) * 16384 + k0 + q8;
    const unsigned short* w0 = WgT + (size_t)(w * 32 + l15) * 16384 + k0 + q8;
    const unsigned short* w1 = w0 + (size_t)16 * 16384;
#pragma unroll 8
    for (int ks = 0; ks < 32; ++ks) {
        int kk = ks * 32;
        bf16x8 af0 = *(const bf16x8*)(x0 + kk);
        bf16x8 bf0 = *(const bf16x8*)(w0 + kk);
        bf16x8 bf1 = *(const bf16x8*)(w1 + kk);
        a00 = __builtin_amdgcn_mfma_f32_16x16x32_bf16(af0, bf0, a00, 0, 0, 0);
        a01 = __builtin_amdgcn_mfma_f32_16x16x32_bf16(af0, bf1, a01, 0, 0, 0);
    }
    int row = (lane >> 4) * 4;
    size_t base = (size_t)split * (B_ * 128);
    float* g = Gpart + base + (size_t)(b0 + row) * 128 + w * 32 + l15;
#pragma unroll
    for (int r = 0; r < 4; ++r) {
        g[(size_t)r * 128] = a00[r];
        g[(size_t)r * 128 + 16] = a01[r];
    }
}

// ---------------------------------------------------------------------------
// per-step small: Ab = sum(Gpart) + rho*AAH*(z-u);  qb = bf16(rho*(z-u) - S^-1*Ab)
__global__ __launch_bounds__(256) void k_small12(const float* Gpart, const float* AAHT,
                                                 const float* Wt, const float* zin,
                                                 const float* uin, const float* lr,
                                                 unsigned short* qb) {
    __shared__ float2 AbS[4][64];
    int t = threadIdx.x;
    int m = t & 63;
    int w = __builtin_amdgcn_readfirstlane(t >> 6);
    int b = blockIdx.x * 4 + w;
    float rho = expf(lr[0]);
    float abR = 0.f, abI = 0.f;
    for (int k = 0; k < 64; ++k) {
        float wr = zin[(b * 2 + 0) * 64 + k] - uin[(b * 2 + 0) * 64 + k];
        float wi = zin[(b * 2 + 1) * 64 + k] - uin[(b * 2 + 1) * 64 + k];
        float2 h = *(const float2*)(AAHT + ((size_t)k * 64 + m) * 2);  // AAH[m][k]
        abR += wr * h.x - wi * h.y;
        abI += wi * h.x + wr * h.y;
    }
    float gR = 0.f, gI = 0.f;
#pragma unroll
    for (int s = 0; s < NSG; ++s) {
        gR += Gpart[(size_t)s * 131072 + (size_t)b * 128 + m];
        gI += Gpart[(size_t)s * 131072 + (size_t)b * 128 + 64 + m];
    }
    abR = gR + rho * abR;
    abI = gI + rho * abI;
    AbS[w][m] = make_float2(abR, abI);
    __syncthreads();
    float tR = 0.f, tI = 0.f;
    for (int k = 0; k < 64; ++k) {
        float2 Wv = *(const float2*)(Wt + ((size_t)k * 64 + m) * 2);   // W[m][k]
        float2 ab = AbS[w][k];
        tR += ab.x * Wv.x - ab.y * Wv.y;
        tI += ab.y * Wv.x + ab.x * Wv.y;
    }
    float wr_m = zin[(b * 2 + 0) * 64 + m] - uin[(b * 2 + 0) * 64 + m];
    float wi_m = zin[(b * 2 + 1) * 64 + m] - uin[(b * 2 + 1) * 64 + m];
    qb[(size_t)b * 128 + m] = f2b(rho * wr_m - tR);
    qb[(size_t)b * 128 + 64 + m] = f2b(rho * wi_m - tI);
}

// ---------------------------------------------------------------------------
// k_H23: fused x-update + Ax partials; last step also writes fp32 out (real)
// and zeros the imag rows (absorbs k_zero_imag). rn read as bf16 (rnb).
//
// r5 diagnosis: at 4 waves/block, grid 512 = 2 blocks/CU = 8 waves/CU (25%
// occupancy cap); counters all-low (Mfma 2.8, VALU 6.6, HBM 20%) -> latency-
// bound on the per-wave serial chain of 128 MFMAs + ~128 L2-latency loads.
// Fix: 8 waves/block (512 thr), each wave takes 128 cols (was 256). Same
// grid, same per-block output, LDS 8*8448=67.6KB (still 2 blocks/CU), but
// 16 waves/CU -> 2x latency hiding and half the per-wave chain.
__global__ __launch_bounds__(512, 2) void k_H23(const unsigned short* qb, const unsigned short* ATb,
                                                const unsigned short* rnb, const unsigned short* Abf,
                                                float* out, float* Axpart, int last) {
    __shared__ __align__(16) char lds_buf[8 * 8448];
    int t = threadIdx.x;
    int lane = t & 63;
    int w = t >> 6;                               // 0..7
    int l15 = lane & 15;
    int q8 = (lane >> 4) * 8;
    int row = (lane >> 4) * 4;
    int slab = blockIdx.x;
    int b0 = blockIdx.y * 16;
    int n0 = slab * 1024 + w * 128;               // 128 cols per wave
    short* xs = (short*)(lds_buf + w * 8448);     // [16][264] bf16 (cols 0..127 used)
    float* rs = (float*)(lds_buf + w * 8448);     // [16][132] fp32 alias (same wave only)

    // ---- phase 1
    bf16x8 a[4];
    const unsigned short* qrow = qb + (size_t)(b0 + l15) * 128 + q8;
#pragma unroll
    for (int ks = 0; ks < 4; ++ks) a[ks] = *(const bf16x8*)(qrow + ks * 32);
#pragma unroll 2
    for (int nt = 0; nt < 8; ++nt) {
        f32x4 acc = {};
        const unsigned short* bbase = ATb + (size_t)(n0 + nt * 16 + l15) * 128 + q8;
#pragma unroll
        for (int ks = 0; ks < 4; ++ks) {
            bf16x8 bf = *(const bf16x8*)(bbase + ks * 32);
            acc = __builtin_amdgcn_mfma_f32_16x16x32_bf16(a[ks], bf, acc, 0, 0, 0);
        }
        int ncol = n0 + nt * 16 + l15;
        int nloc = nt * 16 + l15;
#pragma unroll
        for (int r = 0; r < 4; ++r) {
            size_t ridx = (size_t)(b0 + row + r) * 16384 + ncol;   // real row of rn/out
            float v = fmaxf(acc[r] + b2f(rnb[ridx]), 0.f);
            if (last) out[ridx] = v;
            xs[(row + r) * 264 + nloc] = (short)f2b(v);
        }
    }
    // ---- phase 2 (wave-private x-stage: lgkmcnt orders RAW)
    f32x4 acc8[8] = {};
#pragma unroll
    for (int ks = 0; ks < 4; ++ks) {
        bf16x8 xf = *(const bf16x8*)(xs + l15 * 264 + ks * 32 + q8);
#pragma unroll
        for (int ot = 0; ot < 8; ++ot) {
            const unsigned short* bp = Abf + (size_t)(ot * 16 + l15) * 8192 + n0 + ks * 32 + q8;
            acc8[ot] = __builtin_amdgcn_mfma_f32_16x16x32_bf16(xf, *(const bf16x8*)bp, acc8[ot], 0, 0, 0);
        }
    }
    // ---- phase 3
    __syncthreads();
#pragma unroll
    for (int ot = 0; ot < 8; ++ot)
#pragma unroll
        for (int r = 0; r < 4; ++r)
            rs[(row + r) * 132 + ot * 16 + l15] = acc8[ot][r];
    __syncthreads();
#pragma unroll
    for (int e = t; e < 2048; e += 512) {
        int b = e >> 7, o = e & 127;
        float sAx = 0.f;
#pragma unroll
        for (int ww = 0; ww < 8; ++ww)
            sAx += ((const float*)(lds_buf + ww * 8448))[b * 132 + o];
        Axpart[(size_t)slab * 131072 + (size_t)(b0 + b) * 128 + o] = sAx;
    }
    // ---- zero imag rows of out (absorbed k_zero_imag)
    if (last) {
        float4 z4 = make_float4(0.f, 0.f, 0.f, 0.f);
        for (int e = t; e < 4096; e += 512) {
            int bb = e >> 8, nq = e & 255;
            *(float4*)(out + ((size_t)(b0 + bb) * 2 + 1) * N_ + slab * 1024 + nq * 4) = z4;
        }
    }
}

// ---------------------------------------------------------------------------
// per-step epilogue
__global__ __launch_bounds__(128) void k_small3(const float* Axpart, const float* uin,
                                                const float* y, const float* le,
                                                float* z, float* u, float* uout, int last) {
    __shared__ float red[2];
    int b = blockIdx.x, t = threadIdx.x;
    size_t idx = (size_t)b * 128 + t;
    float ax = 0.f;
#pragma unroll
    for (int s = 0; s < NS3; ++s) ax += Axpart[(size_t)s * 131072 + idx];
    float uo = uin[idx], yv = y[idx];
    float v = ax + uo - yv;
    float sq = v * v;
    for (int off = 32; off > 0; off >>= 1) sq += __shfl_down(sq, off, 64);
    if ((t & 63) == 0) red[t >> 6] = sq;
    __syncthreads();
    float tot = red[0] + red[1];
    float eps = expf(le[0]);
    float scale = fminf(1.f, eps / (sqrtf(tot) + 1e-12f));
    float zv = yv + v * scale;
    float un = uo + ax - zv;
    z[idx] = zv;
    u[idx] = un;
    if (last) uout[idx] = un;
}

// ---------------------------------------------------------------------------
extern "C" void kernel_launch(void* const* d_in, const int* in_sizes, int n_in,
                              void* d_out, int out_size, void* d_ws, size_t ws_size,
                              hipStream_t stream) {
    const float* rn  = (const float*)d_in[0];   // (B,2,N)
    const float* y   = (const float*)d_in[1];   // (B,2,M)
    const float* uin = (const float*)d_in[2];   // (B,2,M)
    const float* A   = (const float*)d_in[3];   // (2,M,N)
    const float* lr  = (const float*)d_in[4];   // log_rho
    const float* le  = (const float*)d_in[5];   // log_epsilon

    float* out = (float*)d_out;
    float* ws  = (float*)d_ws;

    float* Gpart  = ws;                             // 16*131072 = 2,097,152 f
    float* Axpart = Gpart + (size_t)NSG * 131072;   //  8*131072 = 1,048,576 f
    float* S      = Axpart + (size_t)NS3 * 131072;  // 8192
    float* AAHT   = S + 8192;                       // 8192
    float* Wt     = AAHT + 8192;                    // 8192
    float* z      = Wt + 8192;                      // 131072
    float* u      = z + 131072;                     // 131072
    unsigned short* qb  = (unsigned short*)(u + 131072);  // 131,072 us
    unsigned short* rnb = qb + 131072;              // B*2*N  = 16,777,216 us
    unsigned short* WgT = rnb + (size_t)B_ * 16384; // 128*16384 = 2,097,152 us
    unsigned short* Abf = WgT + 2097152;            // 2*64*8192 = 1,048,576 us
    unsigned short* ATb = Abf + 1048576;            // 8192*128  = 1,048,576 us
    float* uout = out + (size_t)B_ * 2 * N_;

    k_prep<<<128, 256, 0, stream>>>(A, Abf, WgT, ATb);
    k_cvt<<<8192, 256, 0, stream>>>(rn, rnb);
    k_Sbuild<<<2080, 256, 0, stream>>>(A, lr, S, AAHT);
    k_Ginv<<<1024, 256, 0, stream>>>(rnb, WgT, Gpart, S, Wt);

    for (int step = 0; step < 3; ++step) {
        const float* zp = (step == 0) ? y   : z;
        const float* up = (step == 0) ? uin : u;
        int last = (step == 2) ? 1 : 0;
        k_small12<<<256, 256, 0, stream>>>(Gpart, AAHT, Wt, zp, up, lr, qb);
        k_H23<<<dim3(NS3, 64), 512, 0, stream>>>(qb, ATb, rnb, Abf, out, Axpart, last);
        k_small3<<<B_, 128, 0, stream>>>(Axpart, up, y, le, z, u, uout, last);
    }
}

// Round 7
// 340.701 us; speedup vs baseline: 1.0839x; 1.0011x over previous
//
#include <hip/hip_runtime.h>

#define B_ 1024
#define M_ 64
#define N_ 8192
#define NSG 16   // k-splits for k_G  (chunk 1024 of K=16384)
#define NS3 8    // n-slabs for k_H23 (1024 cols each)

typedef __attribute__((ext_vector_type(8))) short bf16x8;
typedef __attribute__((ext_vector_type(4))) float f32x4;

__device__ inline unsigned short f2b(float f) {
    union { float f; unsigned u; } v; v.f = f;
    unsigned r = v.u + 0x7FFFu + ((v.u >> 16) & 1u);
    return (unsigned short)(r >> 16);
}
__device__ inline unsigned rne2(float lo, float hi) {
    union { float f; unsigned u; } a, b; a.f = lo; b.f = hi;
    unsigned x = (a.u + 0x7FFFu + ((a.u >> 16) & 1u)) >> 16;
    unsigned y = (b.u + 0x7FFFu + ((b.u >> 16) & 1u)) >> 16;
    return x | (y << 16);
}
__device__ inline float b2f(unsigned short s) {
    union { unsigned u; float f; } v; v.u = ((unsigned)s) << 16; return v.f;
}
// readlane with uniform (dynamic) lane index -> SALU broadcast (r8-proven)
__device__ inline float rl(float v, int l) {
    return __builtin_bit_cast(float, __builtin_amdgcn_readlane(__builtin_bit_cast(int, v), l));
}

// ---------------------------------------------------------------------------
// generic fp32 -> bf16 stream (8 elems/thread)
__global__ __launch_bounds__(256) void k_cvt(const float* src, unsigned short* dst) {
    size_t i = ((size_t)blockIdx.x * 256 + threadIdx.x) * 8;
    float4 f0 = *(const float4*)(src + i);
    float4 f1 = *(const float4*)(src + i + 4);
    union { bf16x8 v; unsigned u[4]; } r;
    r.u[0] = rne2(f0.x, f0.y); r.u[1] = rne2(f0.z, f0.w);
    r.u[2] = rne2(f1.x, f1.y); r.u[3] = rne2(f1.z, f1.w);
    *(bf16x8*)(dst + i) = r.v;
}

// ---------------------------------------------------------------------------
// Fused A-prep (blocks 0..127): one pass over A produces Abf (bf16 copy),
// ATb (transpose, [n][c*64+m]), WgT ([o][k]).
// Blocks 128..2175: zero the imag rows of out (32 MB of constant zeros).
// MOVED here from k_H23-last (r6 counters: H23-last WRITE_SIZE 75 MB at only
// ~1.4 TB/s effective — 32 MB of it was these zeros; prep's 128 blocks leave
// the chip idle, so streaming-store blocks ride along ~free).
__global__ __launch_bounds__(256) void k_prep(const float* A, unsigned short* Abf,
                                              unsigned short* WgT, unsigned short* ATb,
                                              float* out) {
    if (blockIdx.x >= 128) {
        // imag-zero path: 2048 blocks x 16 KB
        int z = blockIdx.x - 128;
        int fi = z * 4096 + threadIdx.x * 16;       // offset in imag space (floats)
        int b = fi >> 13;                           // 8192 floats per imag row
        int n = fi & 8191;
        float4* p = (float4*)(out + (size_t)b * 16384 + 8192 + n);
        float4 z4 = make_float4(0.f, 0.f, 0.f, 0.f);
        p[0] = z4; p[1] = z4; p[2] = z4; p[3] = z4;
        return;
    }
    __shared__ float tile[128][65];
    int n0 = blockIdx.x * 64;
    int t = threadIdx.x;
    int nl = t % 64, r0 = t / 64;
#pragma unroll
    for (int it = 0; it < 32; ++it) {
        int row = r0 + it * 4;                       // row = c*64+m
        tile[row][nl] = A[(size_t)row * N_ + n0 + nl];
    }
    __syncthreads();
    // Abf + WgT (row-major reads of tile)
#pragma unroll
    for (int it = 0; it < 32; ++it) {
        int row = r0 + it * 4;
        float v = tile[row][nl];
        unsigned short bv = f2b(v);
        Abf[(size_t)row * N_ + n0 + nl] = bv;
        if (row < 64) {   // Ar[m]
            WgT[(size_t)row * 16384 + n0 + nl] = bv;                 // o=m,    k-low
            WgT[(size_t)(64 + row) * 16384 + 8192 + n0 + nl] = bv;   // o=64+m, k-high
        } else {          // Ai[m], m=row-64
            int m = row - 64;
            WgT[(size_t)m * 16384 + 8192 + n0 + nl] = f2b(-v);       // o=m,    k-high
            WgT[(size_t)(64 + m) * 16384 + n0 + nl] = bv;            // o=64+m, k-low
        }
    }
    // ATb (transposed reads)
    int o = t % 128, nn0 = t / 128;
#pragma unroll
    for (int it = 0; it < 32; ++it) {
        int nn = nn0 + it * 2;
        ATb[(size_t)(n0 + nn) * 128 + o] = f2b(tile[o][nn]);
    }
}

// ---------------------------------------------------------------------------
// S = I/(rho+1e-12) + A A^H  (complex 64x64, Hermitian). fp32.
__global__ __launch_bounds__(256) void k_Sbuild(const float* A, const float* lr,
                                                float* S, float* AAHT) {
    __shared__ float redS[8];
    int bid = blockIdx.x;
    int i = 0, rem = bid;
    while (rem >= 64 - i) { rem -= 64 - i; ++i; }
    int j = i + rem;                       // i <= j
    int t = threadIdx.x;
    const float* Ar = A;
    const float* Ai = A + (size_t)M_ * N_;
    const float* ari = Ar + (size_t)i * N_;
    const float* aii = Ai + (size_t)i * N_;
    const float* arj = Ar + (size_t)j * N_;
    const float* aij = Ai + (size_t)j * N_;
    float aR = 0.f, aI = 0.f;
#pragma unroll
    for (int it = 0; it < 8; ++it) {
        int n = it * 1024 + t * 4;
        float4 xr = *(const float4*)(ari + n);
        float4 xi = *(const float4*)(aii + n);
        float4 br = *(const float4*)(arj + n);
        float4 bi = *(const float4*)(aij + n);
        aR += xr.x * br.x + xi.x * bi.x + xr.y * br.y + xi.y * bi.y
            + xr.z * br.z + xi.z * bi.z + xr.w * br.w + xi.w * bi.w;
        aI += xi.x * br.x - xr.x * bi.x + xi.y * br.y - xr.y * bi.y
            + xi.z * br.z - xr.z * bi.z + xi.w * br.w - xr.w * bi.w;
    }
    for (int off = 32; off > 0; off >>= 1) {
        aR += __shfl_down(aR, off, 64);
        aI += __shfl_down(aI, off, 64);
    }
    int lane = t & 63, w = t >> 6;
    if (lane == 0) { redS[w * 2] = aR; redS[w * 2 + 1] = aI; }
    __syncthreads();
    if (t == 0) {
        float R = redS[0] + redS[2] + redS[4] + redS[6];
        float I = redS[1] + redS[3] + redS[5] + redS[7];
        float inv_rho = 1.0f / (expf(lr[0]) + 1e-12f);
        float diag = (i == j) ? inv_rho : 0.f;
        S[((size_t)i * 64 + j) * 2 + 0] = R + diag;
        S[((size_t)i * 64 + j) * 2 + 1] = I;
        AAHT[((size_t)j * 64 + i) * 2 + 0] = R;
        AAHT[((size_t)j * 64 + i) * 2 + 1] = I;
        if (i != j) {
            S[((size_t)j * 64 + i) * 2 + 0] = R;
            S[((size_t)j * 64 + i) * 2 + 1] = -I;
            AAHT[((size_t)i * 64 + j) * 2 + 0] = R;
            AAHT[((size_t)i * 64 + j) * 2 + 1] = -I;
        }
    }
}

// ---------------------------------------------------------------------------
// k_Ginv: heterogeneous fused kernel, grid = 1024 (r4 form, UNCHANGED this
// round — r4 measured 57.5us, r6 measured 74.7us on identical code: +-30%
// session noise; serves as the noise A/B reference).
__global__ __launch_bounds__(256, 2) void k_Ginv(const unsigned short* rnb,
                                                 const unsigned short* WgT,
                                                 float* Gpart,
                                                 const float* S, float* Wt) {
    int t = threadIdx.x;
    int lane = t & 63;
    if (blockIdx.x == 0) {
        // ---------------- panel-4 blocked inversion ----------------
        __builtin_amdgcn_s_setprio(1);
        __shared__ float2 Tp[2][4][64];   // [parity][panel col j][row]
        int g = t >> 6;
        float mx0,my0,mx1,my1,mx2,my2,mx3,my3,mx4,my4,mx5,my5,mx6,my6,mx7,my7;
        float mx8,my8,mx9,my9,mx10,my10,mx11,my11,mx12,my12,mx13,my13,mx14,my14,mx15,my15;
        // col mapping: J=4q+j -> c = 16q + 4g + j
#define GJ_INIT(J) { int c = 16 * ((J) >> 2) + 4 * g + ((J) & 3);            \
    float2 v = ((const float2*)S)[(size_t)lane * 64 + c];                    \
    mx##J = v.x; my##J = v.y; }
        GJ_INIT(0) GJ_INIT(1) GJ_INIT(2) GJ_INIT(3) GJ_INIT(4) GJ_INIT(5) GJ_INIT(6) GJ_INIT(7)
        GJ_INIT(8) GJ_INIT(9) GJ_INIT(10) GJ_INIT(11) GJ_INIT(12) GJ_INIT(13) GJ_INIT(14) GJ_INIT(15)
#undef GJ_INIT

#define PIV(JA, JB0, JB1, JB2, jj) {                                         \
    int k = p4 + (jj);                                                       \
    float px = rl(mx##JA, k), py = rl(my##JA, k);                            \
    float d = px * px + py * py;                                             \
    float id = 1.0f / d;                                                     \
    float pix = px * id, piy = -py * id;                                     \
    bool isk = (lane == k);                                                  \
    float a   = isk ? 0.f : 1.f;                                             \
    float fpx = isk ? -pix : (mx##JA * pix - my##JA * piy);                  \
    float fpy = isk ? -piy : (mx##JA * piy + my##JA * pix);                  \
    { float sx = rl(mx##JB0, k), sy = rl(my##JB0, k);                        \
      float nx = a * mx##JB0 - (fpx * sx - fpy * sy);                        \
      float ny = a * my##JB0 - (fpx * sy + fpy * sx);                        \
      mx##JB0 = nx; my##JB0 = ny; }                                          \
    { float sx = rl(mx##JB1, k), sy = rl(my##JB1, k);                        \
      float nx = a * mx##JB1 - (fpx * sx - fpy * sy);                        \
      float ny = a * my##JB1 - (fpx * sy + fpy * sx);                        \
      mx##JB1 = nx; my##JB1 = ny; }                                          \
    { float sx = rl(mx##JB2, k), sy = rl(my##JB2, k);                        \
      float nx = a * mx##JB2 - (fpx * sx - fpy * sy);                        \
      float ny = a * my##JB2 - (fpx * sy + fpy * sx);                        \
      mx##JB2 = nx; my##JB2 = ny; }                                          \
    mx##JA = -fpx; my##JA = -fpy; }

#define FACT4(J0, J1, J2, J3) {                                              \
    PIV(J0, J1, J2, J3, 0) PIV(J1, J0, J2, J3, 1)                            \
    PIV(J2, J0, J1, J3, 2) PIV(J3, J0, J1, J2, 3)                            \
    Tp[buf][0][lane] = make_float2(mx##J0, my##J0);                          \
    Tp[buf][1][lane] = make_float2(mx##J1, my##J1);                          \
    Tp[buf][2][lane] = make_float2(mx##J2, my##J2);                          \
    Tp[buf][3][lane] = make_float2(mx##J3, my##J3); }

        for (int p = 0; p < 16; ++p) {
            const int buf = p & 1;
            const int p4  = p * 4;
            const int q   = p >> 2;
            const bool own = (g == (p & 3));
            if (own) {
                switch (q) {
                    case 0:  FACT4(0, 1, 2, 3)     break;
                    case 1:  FACT4(4, 5, 6, 7)     break;
                    case 2:  FACT4(8, 9, 10, 11)   break;
                    default: FACT4(12, 13, 14, 15) break;
                }
            }
            __syncthreads();
            float2 t0 = Tp[buf][0][lane];
            float2 t1 = Tp[buf][1][lane];
            float2 t2 = Tp[buf][2][lane];
            float2 t3 = Tp[buf][3][lane];
            float msk = ((lane >> 2) == p) ? 0.f : 1.f;
            int skipq = own ? q : -1;
#define TRAIL(J) if (((J) >> 2) != skipq) {                                  \
    float s0x = rl(mx##J, p4),     s0y = rl(my##J, p4);                      \
    float s1x = rl(mx##J, p4 + 1), s1y = rl(my##J, p4 + 1);                  \
    float s2x = rl(mx##J, p4 + 2), s2y = rl(my##J, p4 + 2);                  \
    float s3x = rl(mx##J, p4 + 3), s3y = rl(my##J, p4 + 3);                  \
    float ax = msk * mx##J, ay = msk * my##J;                                \
    ax += t0.x * s0x - t0.y * s0y; ay += t0.x * s0y + t0.y * s0x;            \
    ax += t1.x * s1x - t1.y * s1y; ay += t1.x * s1y + t1.y * s1x;            \
    ax += t2.x * s2x - t2.y * s2y; ay += t2.x * s2y + t2.y * s2x;            \
    ax += t3.x * s3x - t3.y * s3y; ay += t3.x * s3y + t3.y * s3x;            \
    mx##J = ax; my##J = ay; }
            TRAIL(0)  TRAIL(1)  TRAIL(2)  TRAIL(3)
            TRAIL(4)  TRAIL(5)  TRAIL(6)  TRAIL(7)
            TRAIL(8)  TRAIL(9)  TRAIL(10) TRAIL(11)
            TRAIL(12) TRAIL(13) TRAIL(14) TRAIL(15)
#undef TRAIL
        }
#undef FACT4
#undef PIV
#define GJ_OUT(J) { int c = 16 * ((J) >> 2) + 4 * g + ((J) & 3);             \
    ((float2*)Wt)[(size_t)c * 64 + lane] = make_float2(mx##J, my##J); }
        GJ_OUT(0) GJ_OUT(1) GJ_OUT(2) GJ_OUT(3) GJ_OUT(4) GJ_OUT(5) GJ_OUT(6) GJ_OUT(7)
        GJ_OUT(8) GJ_OUT(9) GJ_OUT(10) GJ_OUT(11) GJ_OUT(12) GJ_OUT(13) GJ_OUT(14) GJ_OUT(15)
#undef GJ_OUT
        __builtin_amdgcn_s_setprio(0);
        // fall through: block 0 also runs its GEMM chunk (bx = 0)
    }
    // ---------------- GEMM path (k_G) ----------------
    int bx = blockIdx.x;
    int w = t >> 6;
    int l15 = lane & 15;
    int q8 = (lane >> 4) * 8;
    int split = bx & 15;
    int b0 = (bx >> 4) * 16;
    int k0 = split * 1024;
    f32x4 a00 = {}, a01 = {};
    const unsigned short* x0 = rnb + (size_t)(b0 + l15) * 16384 + k0 + q8;
    const unsigned short* w0 = WgT + (size_t)(w * 32 + l15) * 16384 + k0 + q8;
    const unsigned short* w1 = w0 + (size_t)16 * 16384;
#pragma unroll 8
    for (int ks = 0; ks < 32; ++ks) {
        int kk = ks * 32;
        bf16x8 af0 = *(const bf16x8*)(x0 + kk);
        bf16x8 bf0 = *(const bf16x8*)(w0 + kk);
        bf16x8 bf1 = *(const bf16x8*)(w1 + kk);
        a00 = __builtin_amdgcn_mfma_f32_16x16x32_bf16(af0, bf0, a00, 0, 0, 0);
        a01 = __builtin_amdgcn_mfma_f32_16x16x32_bf16(af0, bf1, a01, 0, 0, 0);
    }
    int row = (lane >> 4) * 4;
    size_t base = (size_t)split * (B_ * 128);
    float* g = Gpart + base + (size_t)(b0 + row) * 128 + w * 32 + l15;
#pragma unroll
    for (int r = 0; r < 4; ++r) {
        g[(size_t)r * 128] = a00[r];
        g[(size_t)r * 128 + 16] = a01[r];
    }
}

// ---------------------------------------------------------------------------
// per-step small: Ab = sum(Gpart) + rho*AAH*(z-u);  qb = bf16(rho*(z-u) - S^-1*Ab)
//
// r7 restructure: was 256 blocks x (1 wave = 1 batch, 64+64 serial k-iters)
// = 1 block/CU = 4 waves/CU (12.5% occupancy cap) — latency-bound (all
// counters low). Now: 1 block per batch (grid 1024), 4 waves split each
// 64-k loop 16-each with LDS partial reduction -> 16 waves/CU and a 4x
// shorter per-wave dependent chain. partA/partB separate (no WAR race).
__global__ __launch_bounds__(256) void k_small12(const float* Gpart, const float* AAHT,
                                                 const float* Wt, const float* zin,
                                                 const float* uin, const float* lr,
                                                 unsigned short* qb) {
    __shared__ float2 partA[4][64];
    __shared__ float2 partB[4][64];
    __shared__ float2 AbS[64];
    int t = threadIdx.x;
    int m = t & 63;
    int w = __builtin_amdgcn_readfirstlane(t >> 6);   // 0..3: k-split
    int b = blockIdx.x;
    float rho = expf(lr[0]);
    // ---- phase A: partial Ab over k in [w*16, w*16+16)
    float aR = 0.f, aI = 0.f;
#pragma unroll
    for (int kk = 0; kk < 16; ++kk) {
        int k = w * 16 + kk;
        float wr = zin[(b * 2 + 0) * 64 + k] - uin[(b * 2 + 0) * 64 + k];
        float wi = zin[(b * 2 + 1) * 64 + k] - uin[(b * 2 + 1) * 64 + k];
        float2 h = *(const float2*)(AAHT + ((size_t)k * 64 + m) * 2);  // AAH[m][k]
        aR += wr * h.x - wi * h.y;
        aI += wi * h.x + wr * h.y;
    }
    aR *= rho; aI *= rho;
    // Gpart slices s = w*4 .. w*4+3
#pragma unroll
    for (int s4 = 0; s4 < 4; ++s4) {
        int s = w * 4 + s4;
        aR += Gpart[(size_t)s * 131072 + (size_t)b * 128 + m];
        aI += Gpart[(size_t)s * 131072 + (size_t)b * 128 + 64 + m];
    }
    partA[w][m] = make_float2(aR, aI);
    __syncthreads();
    if (w == 0) {
        float2 p0 = partA[0][m], p1 = partA[1][m], p2 = partA[2][m], p3 = partA[3][m];
        AbS[m] = make_float2(p0.x + p1.x + p2.x + p3.x, p0.y + p1.y + p2.y + p3.y);
    }
    __syncthreads();
    // ---- phase B: partial T = W * Ab over k in [w*16, w*16+16)
    float tR = 0.f, tI = 0.f;
#pragma unroll
    for (int kk = 0; kk < 16; ++kk) {
        int k = w * 16 + kk;
        float2 Wv = *(const float2*)(Wt + ((size_t)k * 64 + m) * 2);   // W[m][k]
        float2 ab = AbS[k];                                            // broadcast
        tR += ab.x * Wv.x - ab.y * Wv.y;
        tI += ab.y * Wv.x + ab.x * Wv.y;
    }
    partB[w][m] = make_float2(tR, tI);
    __syncthreads();
    if (w == 0) {
        float2 q0 = partB[0][m], q1 = partB[1][m], q2 = partB[2][m], q3 = partB[3][m];
        float sR = q0.x + q1.x + q2.x + q3.x;
        float sI = q0.y + q1.y + q2.y + q3.y;
        float wr_m = zin[(b * 2 + 0) * 64 + m] - uin[(b * 2 + 0) * 64 + m];
        float wi_m = zin[(b * 2 + 1) * 64 + m] - uin[(b * 2 + 1) * 64 + m];
        qb[(size_t)b * 128 + m] = f2b(rho * wr_m - sR);
        qb[(size_t)b * 128 + 64 + m] = f2b(rho * wi_m - sI);
    }
}

// ---------------------------------------------------------------------------
// k_H23: fused x-update + Ax partials; last step also writes fp32 out (real).
// (imag-row zeroing moved to k_prep — removes 32 MB of constant-zero writes
// from this kernel's last-step critical path.)
__global__ __launch_bounds__(512, 2) void k_H23(const unsigned short* qb, const unsigned short* ATb,
                                                const unsigned short* rnb, const unsigned short* Abf,
                                                float* out, float* Axpart, int last) {
    __shared__ __align__(16) char lds_buf[8 * 8448];
    int t = threadIdx.x;
    int lane = t & 63;
    int w = t >> 6;                               // 0..7
    int l15 = lane & 15;
    int q8 = (lane >> 4) * 8;
    int row = (lane >> 4) * 4;
    int slab = blockIdx.x;
    int b0 = blockIdx.y * 16;
    int n0 = slab * 1024 + w * 128;               // 128 cols per wave
    short* xs = (short*)(lds_buf + w * 8448);     // [16][264] bf16 (cols 0..127 used)
    float* rs = (float*)(lds_buf + w * 8448);     // [16][132] fp32 alias (same wave only)

    // ---- phase 1
    bf16x8 a[4];
    const unsigned short* qrow = qb + (size_t)(b0 + l15) * 128 + q8;
#pragma unroll
    for (int ks = 0; ks < 4; ++ks) a[ks] = *(const bf16x8*)(qrow + ks * 32);
#pragma unroll 2
    for (int nt = 0; nt < 8; ++nt) {
        f32x4 acc = {};
        const unsigned short* bbase = ATb + (size_t)(n0 + nt * 16 + l15) * 128 + q8;
#pragma unroll
        for (int ks = 0; ks < 4; ++ks) {
            bf16x8 bf = *(const bf16x8*)(bbase + ks * 32);
            acc = __builtin_amdgcn_mfma_f32_16x16x32_bf16(a[ks], bf, acc, 0, 0, 0);
        }
        int ncol = n0 + nt * 16 + l15;
        int nloc = nt * 16 + l15;
#pragma unroll
        for (int r = 0; r < 4; ++r) {
            size_t ridx = (size_t)(b0 + row + r) * 16384 + ncol;   // real row of rn/out
            float v = fmaxf(acc[r] + b2f(rnb[ridx]), 0.f);
            if (last) out[ridx] = v;
            xs[(row + r) * 264 + nloc] = (short)f2b(v);
        }
    }
    // ---- phase 2 (wave-private x-stage: lgkmcnt orders RAW)
    f32x4 acc8[8] = {};
#pragma unroll
    for (int ks = 0; ks < 4; ++ks) {
        bf16x8 xf = *(const bf16x8*)(xs + l15 * 264 + ks * 32 + q8);
#pragma unroll
        for (int ot = 0; ot < 8; ++ot) {
            const unsigned short* bp = Abf + (size_t)(ot * 16 + l15) * 8192 + n0 + ks * 32 + q8;
            acc8[ot] = __builtin_amdgcn_mfma_f32_16x16x32_bf16(xf, *(const bf16x8*)bp, acc8[ot], 0, 0, 0);
        }
    }
    // ---- phase 3
    __syncthreads();
#pragma unroll
    for (int ot = 0; ot < 8; ++ot)
#pragma unroll
        for (int r = 0; r < 4; ++r)
            rs[(row + r) * 132 + ot * 16 + l15] = acc8[ot][r];
    __syncthreads();
#pragma unroll
    for (int e = t; e < 2048; e += 512) {
        int b = e >> 7, o = e & 127;
        float sAx = 0.f;
#pragma unroll
        for (int ww = 0; ww < 8; ++ww)
            sAx += ((const float*)(lds_buf + ww * 8448))[b * 132 + o];
        Axpart[(size_t)slab * 131072 + (size_t)(b0 + b) * 128 + o] = sAx;
    }
}

// ---------------------------------------------------------------------------
// per-step epilogue
__global__ __launch_bounds__(128) void k_small3(const float* Axpart, const float* uin,
                                                const float* y, const float* le,
                                                float* z, float* u, float* uout, int last) {
    __shared__ float red[2];
    int b = blockIdx.x, t = threadIdx.x;
    size_t idx = (size_t)b * 128 + t;
    float ax = 0.f;
#pragma unroll
    for (int s = 0; s < NS3; ++s) ax += Axpart[(size_t)s * 131072 + idx];
    float uo = uin[idx], yv = y[idx];
    float v = ax + uo - yv;
    float sq = v * v;
    for (int off = 32; off > 0; off >>= 1) sq += __shfl_down(sq, off, 64);
    if ((t & 63) == 0) red[t >> 6] = sq;
    __syncthreads();
    float tot = red[0] + red[1];
    float eps = expf(le[0]);
    float scale = fminf(1.f, eps / (sqrtf(tot) + 1e-12f));
    float zv = yv + v * scale;
    float un = uo + ax - zv;
    z[idx] = zv;
    u[idx] = un;
    if (last) uout[idx] = un;
}

// ---------------------------------------------------------------------------
extern "C" void kernel_launch(void* const* d_in, const int* in_sizes, int n_in,
                              void* d_out, int out_size, void* d_ws, size_t ws_size,
                              hipStream_t stream) {
    const float* rn  = (const float*)d_in[0];   // (B,2,N)
    const float* y   = (const float*)d_in[1];   // (B,2,M)
    const float* uin = (const float*)d_in[2];   // (B,2,M)
    const float* A   = (const float*)d_in[3];   // (2,M,N)
    const float* lr  = (const float*)d_in[4];   // log_rho
    const float* le  = (const float*)d_in[5];   // log_epsilon

    float* out = (float*)d_out;
    float* ws  = (float*)d_ws;

    float* Gpart  = ws;                             // 16*131072 = 2,097,152 f
    float* Axpart = Gpart + (size_t)NSG * 131072;   //  8*131072 = 1,048,576 f
    float* S      = Axpart + (size_t)NS3 * 131072;  // 8192
    float* AAHT   = S + 8192;                       // 8192
    float* Wt     = AAHT + 8192;                    // 8192
    float* z      = Wt + 8192;                      // 131072
    float* u      = z + 131072;                     // 131072
    unsigned short* qb  = (unsigned short*)(u + 131072);  // 131,072 us
    unsigned short* rnb = qb + 131072;              // B*2*N  = 16,777,216 us
    unsigned short* WgT = rnb + (size_t)B_ * 16384; // 128*16384 = 2,097,152 us
    unsigned short* Abf = WgT + 2097152;            // 2*64*8192 = 1,048,576 us
    unsigned short* ATb = Abf + 1048576;            // 8192*128  = 1,048,576 us
    float* uout = out + (size_t)B_ * 2 * N_;

    k_prep<<<2176, 256, 0, stream>>>(A, Abf, WgT, ATb, out);   // 128 prep + 2048 imag-zero
    k_cvt<<<8192, 256, 0, stream>>>(rn, rnb);
    k_Sbuild<<<2080, 256, 0, stream>>>(A, lr, S, AAHT);
    k_Ginv<<<1024, 256, 0, stream>>>(rnb, WgT, Gpart, S, Wt);

    for (int step = 0; step < 3; ++step) {
        const float* zp = (step == 0) ? y   : z;
        const float* up = (step == 0) ? uin : u;
        int last = (step == 2) ? 1 : 0;
        k_small12<<<B_, 256, 0, stream>>>(Gpart, AAHT, Wt, zp, up, lr, qb);
        k_H23<<<dim3(NS3, 64), 512, 0, stream>>>(qb, ATb, rnb, Abf, out, Axpart, last);
        k_small3<<<B_, 128, 0, stream>>>(Axpart, up, y, le, z, u, uout, last);
    }
}

// Round 8
// 337.936 us; speedup vs baseline: 1.0928x; 1.0082x over previous
//
#include <hip/hip_runtime.h>

#define B_ 1024
#define M_ 64
#define N_ 8192
#define NSG 16   // k-splits for k_G  (chunk 1024 of K=16384)
#define NS3 8    // n-slabs for k_H23 (1024 cols each)

typedef __attribute__((ext_vector_type(8))) short bf16x8;
typedef __attribute__((ext_vector_type(4))) float f32x4;

__device__ inline unsigned short f2b(float f) {
    union { float f; unsigned u; } v; v.f = f;
    unsigned r = v.u + 0x7FFFu + ((v.u >> 16) & 1u);
    return (unsigned short)(r >> 16);
}
__device__ inline unsigned rne2(float lo, float hi) {
    union { float f; unsigned u; } a, b; a.f = lo; b.f = hi;
    unsigned x = (a.u + 0x7FFFu + ((a.u >> 16) & 1u)) >> 16;
    unsigned y = (b.u + 0x7FFFu + ((b.u >> 16) & 1u)) >> 16;
    return x | (y << 16);
}
__device__ inline float b2f(unsigned short s) {
    union { unsigned u; float f; } v; v.u = ((unsigned)s) << 16; return v.f;
}
// readlane with uniform (dynamic) lane index -> SALU broadcast (r8-proven)
__device__ inline float rl(float v, int l) {
    return __builtin_bit_cast(float, __builtin_amdgcn_readlane(__builtin_bit_cast(int, v), l));
}

// ---------------------------------------------------------------------------
// generic fp32 -> bf16 stream (8 elems/thread)
__global__ __launch_bounds__(256) void k_cvt(const float* src, unsigned short* dst) {
    size_t i = ((size_t)blockIdx.x * 256 + threadIdx.x) * 8;
    float4 f0 = *(const float4*)(src + i);
    float4 f1 = *(const float4*)(src + i + 4);
    union { bf16x8 v; unsigned u[4]; } r;
    r.u[0] = rne2(f0.x, f0.y); r.u[1] = rne2(f0.z, f0.w);
    r.u[2] = rne2(f1.x, f1.y); r.u[3] = rne2(f1.z, f1.w);
    *(bf16x8*)(dst + i) = r.v;
}

// ---------------------------------------------------------------------------
// Fused A-prep (blocks 0..127) + imag-row zeroing of out (blocks 128..2175).
__global__ __launch_bounds__(256) void k_prep(const float* A, unsigned short* Abf,
                                              unsigned short* WgT, unsigned short* ATb,
                                              float* out) {
    if (blockIdx.x >= 128) {
        int z = blockIdx.x - 128;
        int fi = z * 4096 + threadIdx.x * 16;       // offset in imag space (floats)
        int b = fi >> 13;                           // 8192 floats per imag row
        int n = fi & 8191;
        float4* p = (float4*)(out + (size_t)b * 16384 + 8192 + n);
        float4 z4 = make_float4(0.f, 0.f, 0.f, 0.f);
        p[0] = z4; p[1] = z4; p[2] = z4; p[3] = z4;
        return;
    }
    __shared__ float tile[128][65];
    int n0 = blockIdx.x * 64;
    int t = threadIdx.x;
    int nl = t % 64, r0 = t / 64;
#pragma unroll
    for (int it = 0; it < 32; ++it) {
        int row = r0 + it * 4;                       // row = c*64+m
        tile[row][nl] = A[(size_t)row * N_ + n0 + nl];
    }
    __syncthreads();
#pragma unroll
    for (int it = 0; it < 32; ++it) {
        int row = r0 + it * 4;
        float v = tile[row][nl];
        unsigned short bv = f2b(v);
        Abf[(size_t)row * N_ + n0 + nl] = bv;
        if (row < 64) {   // Ar[m]
            WgT[(size_t)row * 16384 + n0 + nl] = bv;                 // o=m,    k-low
            WgT[(size_t)(64 + row) * 16384 + 8192 + n0 + nl] = bv;   // o=64+m, k-high
        } else {          // Ai[m], m=row-64
            int m = row - 64;
            WgT[(size_t)m * 16384 + 8192 + n0 + nl] = f2b(-v);       // o=m,    k-high
            WgT[(size_t)(64 + m) * 16384 + n0 + nl] = bv;            // o=64+m, k-low
        }
    }
    int o = t % 128, nn0 = t / 128;
#pragma unroll
    for (int it = 0; it < 32; ++it) {
        int nn = nn0 + it * 2;
        ATb[(size_t)(n0 + nn) * 128 + o] = f2b(tile[o][nn]);
    }
}

// ---------------------------------------------------------------------------
// S = I/(rho+1e-12) + A A^H  (complex 64x64, Hermitian). fp32.
__global__ __launch_bounds__(256) void k_Sbuild(const float* A, const float* lr,
                                                float* S, float* AAHT) {
    __shared__ float redS[8];
    int bid = blockIdx.x;
    int i = 0, rem = bid;
    while (rem >= 64 - i) { rem -= 64 - i; ++i; }
    int j = i + rem;                       // i <= j
    int t = threadIdx.x;
    const float* Ar = A;
    const float* Ai = A + (size_t)M_ * N_;
    const float* ari = Ar + (size_t)i * N_;
    const float* aii = Ai + (size_t)i * N_;
    const float* arj = Ar + (size_t)j * N_;
    const float* aij = Ai + (size_t)j * N_;
    float aR = 0.f, aI = 0.f;
#pragma unroll
    for (int it = 0; it < 8; ++it) {
        int n = it * 1024 + t * 4;
        float4 xr = *(const float4*)(ari + n);
        float4 xi = *(const float4*)(aii + n);
        float4 br = *(const float4*)(arj + n);
        float4 bi = *(const float4*)(aij + n);
        aR += xr.x * br.x + xi.x * bi.x + xr.y * br.y + xi.y * bi.y
            + xr.z * br.z + xi.z * bi.z + xr.w * br.w + xi.w * bi.w;
        aI += xi.x * br.x - xr.x * bi.x + xi.y * br.y - xr.y * bi.y
            + xi.z * br.z - xr.z * bi.z + xi.w * br.w - xr.w * bi.w;
    }
    for (int off = 32; off > 0; off >>= 1) {
        aR += __shfl_down(aR, off, 64);
        aI += __shfl_down(aI, off, 64);
    }
    int lane = t & 63, w = t >> 6;
    if (lane == 0) { redS[w * 2] = aR; redS[w * 2 + 1] = aI; }
    __syncthreads();
    if (t == 0) {
        float R = redS[0] + redS[2] + redS[4] + redS[6];
        float I = redS[1] + redS[3] + redS[5] + redS[7];
        float inv_rho = 1.0f / (expf(lr[0]) + 1e-12f);
        float diag = (i == j) ? inv_rho : 0.f;
        S[((size_t)i * 64 + j) * 2 + 0] = R + diag;
        S[((size_t)i * 64 + j) * 2 + 1] = I;
        AAHT[((size_t)j * 64 + i) * 2 + 0] = R;
        AAHT[((size_t)j * 64 + i) * 2 + 1] = I;
        if (i != j) {
            S[((size_t)j * 64 + i) * 2 + 0] = R;
            S[((size_t)j * 64 + i) * 2 + 1] = -I;
            AAHT[((size_t)i * 64 + j) * 2 + 0] = R;
            AAHT[((size_t)i * 64 + j) * 2 + 1] = -I;
        }
    }
}

// ---------------------------------------------------------------------------
// k_Ginv: heterogeneous fused kernel, grid = 512.
//   block 0        : PANEL-4 blocked GJ inverse of S -> Wt, then falls through.
//   all blocks     : GEMM with BATCH-TILE 32 (was 16): r7 counters showed the
//                    GEMM is L2/L3-traffic-bound (MfmaUtil 2%, ~295 MB cache
//                    traffic for 4.3 GFLOP). Doubling the batch tile halves
//                    WgT traffic per output (295 -> 164 MB): 4 acc/wave,
//                    4 loads + 4 MFMAs per k-iter. Grid 512 = 2 blocks/CU,
//                    co-resident from t=0 (VGPR << 128), GJ overlap unchanged.
__global__ __launch_bounds__(256, 2) void k_Ginv(const unsigned short* rnb,
                                                 const unsigned short* WgT,
                                                 float* Gpart,
                                                 const float* S, float* Wt) {
    int t = threadIdx.x;
    int lane = t & 63;
    if (blockIdx.x == 0) {
        // ---------------- panel-4 blocked inversion ----------------
        __builtin_amdgcn_s_setprio(1);
        __shared__ float2 Tp[2][4][64];   // [parity][panel col j][row]
        int g = t >> 6;
        float mx0,my0,mx1,my1,mx2,my2,mx3,my3,mx4,my4,mx5,my5,mx6,my6,mx7,my7;
        float mx8,my8,mx9,my9,mx10,my10,mx11,my11,mx12,my12,mx13,my13,mx14,my14,mx15,my15;
        // col mapping: J=4q+j -> c = 16q + 4g + j
#define GJ_INIT(J) { int c = 16 * ((J) >> 2) + 4 * g + ((J) & 3);            \
    float2 v = ((const float2*)S)[(size_t)lane * 64 + c];                    \
    mx##J = v.x; my##J = v.y; }
        GJ_INIT(0) GJ_INIT(1) GJ_INIT(2) GJ_INIT(3) GJ_INIT(4) GJ_INIT(5) GJ_INIT(6) GJ_INIT(7)
        GJ_INIT(8) GJ_INIT(9) GJ_INIT(10) GJ_INIT(11) GJ_INIT(12) GJ_INIT(13) GJ_INIT(14) GJ_INIT(15)
#undef GJ_INIT

#define PIV(JA, JB0, JB1, JB2, jj) {                                         \
    int k = p4 + (jj);                                                       \
    float px = rl(mx##JA, k), py = rl(my##JA, k);                            \
    float d = px * px + py * py;                                             \
    float id = 1.0f / d;                                                     \
    float pix = px * id, piy = -py * id;                                     \
    bool isk = (lane == k);                                                  \
    float a   = isk ? 0.f : 1.f;                                             \
    float fpx = isk ? -pix : (mx##JA * pix - my##JA * piy);                  \
    float fpy = isk ? -piy : (mx##JA * piy + my##JA * pix);                  \
    { float sx = rl(mx##JB0, k), sy = rl(my##JB0, k);                        \
      float nx = a * mx##JB0 - (fpx * sx - fpy * sy);                        \
      float ny = a * my##JB0 - (fpx * sy + fpy * sx);                        \
      mx##JB0 = nx; my##JB0 = ny; }                                          \
    { float sx = rl(mx##JB1, k), sy = rl(my##JB1, k);                        \
      float nx = a * mx##JB1 - (fpx * sx - fpy * sy);                        \
      float ny = a * my##JB1 - (fpx * sy + fpy * sx);                        \
      mx##JB1 = nx; my##JB1 = ny; }                                          \
    { float sx = rl(mx##JB2, k), sy = rl(my##JB2, k);                        \
      float nx = a * mx##JB2 - (fpx * sx - fpy * sy);                        \
      float ny = a * my##JB2 - (fpx * sy + fpy * sx);                        \
      mx##JB2 = nx; my##JB2 = ny; }                                          \
    mx##JA = -fpx; my##JA = -fpy; }

#define FACT4(J0, J1, J2, J3) {                                              \
    PIV(J0, J1, J2, J3, 0) PIV(J1, J0, J2, J3, 1)                            \
    PIV(J2, J0, J1, J3, 2) PIV(J3, J0, J1, J2, 3)                            \
    Tp[buf][0][lane] = make_float2(mx##J0, my##J0);                          \
    Tp[buf][1][lane] = make_float2(mx##J1, my##J1);                          \
    Tp[buf][2][lane] = make_float2(mx##J2, my##J2);                          \
    Tp[buf][3][lane] = make_float2(mx##J3, my##J3); }

        for (int p = 0; p < 16; ++p) {
            const int buf = p & 1;
            const int p4  = p * 4;
            const int q   = p >> 2;
            const bool own = (g == (p & 3));
            if (own) {
                switch (q) {
                    case 0:  FACT4(0, 1, 2, 3)     break;
                    case 1:  FACT4(4, 5, 6, 7)     break;
                    case 2:  FACT4(8, 9, 10, 11)   break;
                    default: FACT4(12, 13, 14, 15) break;
                }
            }
            __syncthreads();
            float2 t0 = Tp[buf][0][lane];
            float2 t1 = Tp[buf][1][lane];
            float2 t2 = Tp[buf][2][lane];
            float2 t3 = Tp[buf][3][lane];
            float msk = ((lane >> 2) == p) ? 0.f : 1.f;
            int skipq = own ? q : -1;
#define TRAIL(J) if (((J) >> 2) != skipq) {                                  \
    float s0x = rl(mx##J, p4),     s0y = rl(my##J, p4);                      \
    float s1x = rl(mx##J, p4 + 1), s1y = rl(my##J, p4 + 1);                  \
    float s2x = rl(mx##J, p4 + 2), s2y = rl(my##J, p4 + 2);                  \
    float s3x = rl(mx##J, p4 + 3), s3y = rl(my##J, p4 + 3);                  \
    float ax = msk * mx##J, ay = msk * my##J;                                \
    ax += t0.x * s0x - t0.y * s0y; ay += t0.x * s0y + t0.y * s0x;            \
    ax += t1.x * s1x - t1.y * s1y; ay += t1.x * s1y + t1.y * s1x;            \
    ax += t2.x * s2x - t2.y * s2y; ay += t2.x * s2y + t2.y * s2x;            \
    ax += t3.x * s3x - t3.y * s3y; ay += t3.x * s3y + t3.y * s3x;            \
    mx##J = ax; my##J = ay; }
            TRAIL(0)  TRAIL(1)  TRAIL(2)  TRAIL(3)
            TRAIL(4)  TRAIL(5)  TRAIL(6)  TRAIL(7)
            TRAIL(8)  TRAIL(9)  TRAIL(10) TRAIL(11)
            TRAIL(12) TRAIL(13) TRAIL(14) TRAIL(15)
#undef TRAIL
        }
#undef FACT4
#undef PIV
#define GJ_OUT(J) { int c = 16 * ((J) >> 2) + 4 * g + ((J) & 3);             \
    ((float2*)Wt)[(size_t)c * 64 + lane] = make_float2(mx##J, my##J); }
        GJ_OUT(0) GJ_OUT(1) GJ_OUT(2) GJ_OUT(3) GJ_OUT(4) GJ_OUT(5) GJ_OUT(6) GJ_OUT(7)
        GJ_OUT(8) GJ_OUT(9) GJ_OUT(10) GJ_OUT(11) GJ_OUT(12) GJ_OUT(13) GJ_OUT(14) GJ_OUT(15)
#undef GJ_OUT
        __builtin_amdgcn_s_setprio(0);
        // fall through: block 0 also runs its GEMM chunk (bx = 0)
    }
    // ---------------- GEMM path: batch-tile 32 ----------------
    int bx = blockIdx.x;
    int w = t >> 6;
    int l15 = lane & 15;
    int q8 = (lane >> 4) * 8;
    int split = bx & 15;
    int b0 = (bx >> 4) * 32;
    int k0 = split * 1024;
    f32x4 a00 = {}, a01 = {}, a10 = {}, a11 = {};
    const unsigned short* x0 = rnb + (size_t)(b0 + l15) * 16384 + k0 + q8;
    const unsigned short* x1 = x0 + (size_t)16 * 16384;
    const unsigned short* w0 = WgT + (size_t)(w * 32 + l15) * 16384 + k0 + q8;
    const unsigned short* w1 = w0 + (size_t)16 * 16384;
#pragma unroll 8
    for (int ks = 0; ks < 32; ++ks) {
        int kk = ks * 32;
        bf16x8 af0 = *(const bf16x8*)(x0 + kk);
        bf16x8 af1 = *(const bf16x8*)(x1 + kk);
        bf16x8 bf0 = *(const bf16x8*)(w0 + kk);
        bf16x8 bf1 = *(const bf16x8*)(w1 + kk);
        a00 = __builtin_amdgcn_mfma_f32_16x16x32_bf16(af0, bf0, a00, 0, 0, 0);
        a01 = __builtin_amdgcn_mfma_f32_16x16x32_bf16(af0, bf1, a01, 0, 0, 0);
        a10 = __builtin_amdgcn_mfma_f32_16x16x32_bf16(af1, bf0, a10, 0, 0, 0);
        a11 = __builtin_amdgcn_mfma_f32_16x16x32_bf16(af1, bf1, a11, 0, 0, 0);
    }
    int row = (lane >> 4) * 4;
    size_t base = (size_t)split * (B_ * 128);
    float* g  = Gpart + base + (size_t)(b0 + row) * 128 + w * 32 + l15;
    float* g2 = g + 16 * 128;
#pragma unroll
    for (int r = 0; r < 4; ++r) {
        g[(size_t)r * 128]       = a00[r];
        g[(size_t)r * 128 + 16]  = a01[r];
        g2[(size_t)r * 128]      = a10[r];
        g2[(size_t)r * 128 + 16] = a11[r];
    }
}

// ---------------------------------------------------------------------------
// k_F: fused per-step kernel = small3(step i-1) + small12(step i).
//   have_ax=0 (step 0): w = y - uin straight from inputs.
//   have_ax=1: s3-part (threads 0..127): ax = sum(Axpart), v = ax+uo-y,
//     norm-clip -> zv, un; writes u (needed next step), w = zv-un to LDS.
//   Then all 4 waves run the k-split small12 (r7 structure) reading w from
//   LDS instead of z/u global round-trip. Removes 2 launches/loop + the z
//   buffer entirely; arithmetic bitwise-identical to the unfused pair.
__global__ __launch_bounds__(256) void k_F(const float* Gpart, const float* AAHT,
                                           const float* Wt, const float* Axpart,
                                           const float* y, const float* uprev,
                                           float* u, const float* lr, const float* le,
                                           unsigned short* qb, int have_ax) {
    __shared__ float wS[128];
    __shared__ float2 partA[4][64];
    __shared__ float2 partB[4][64];
    __shared__ float2 AbS[64];
    __shared__ float red[2];
    int t = threadIdx.x;
    int b = blockIdx.x;
    float rho = expf(lr[0]);
    if (have_ax) {
        float vv = 0.f, uo = 0.f, yv = 0.f, ax = 0.f;
        if (t < 128) {
            size_t idx = (size_t)b * 128 + t;
            #pragma unroll
            for (int s = 0; s < NS3; ++s) ax += Axpart[(size_t)s * 131072 + idx];
            uo = uprev[idx]; yv = y[idx];
            vv = ax + uo - yv;
            float sq = vv * vv;
            for (int off = 32; off > 0; off >>= 1) sq += __shfl_down(sq, off, 64);
            if ((t & 63) == 0) red[t >> 6] = sq;
        }
        __syncthreads();
        if (t < 128) {
            float tot = red[0] + red[1];
            float eps = expf(le[0]);
            float scale = fminf(1.f, eps / (sqrtf(tot) + 1e-12f));
            float zv = yv + vv * scale;
            float un = uo + ax - zv;
            u[(size_t)b * 128 + t] = un;
            wS[t] = zv - un;
        }
    } else {
        if (t < 128) {
            size_t idx = (size_t)b * 128 + t;
            wS[t] = y[idx] - uprev[idx];
        }
    }
    __syncthreads();
    // ---- small12 phases (r7 k-split structure), w from LDS
    int m = t & 63;
    int w = __builtin_amdgcn_readfirstlane(t >> 6);   // 0..3: k-split
    float aR = 0.f, aI = 0.f;
#pragma unroll
    for (int kk = 0; kk < 16; ++kk) {
        int k = w * 16 + kk;
        float wr = wS[k];
        float wi = wS[64 + k];
        float2 h = *(const float2*)(AAHT + ((size_t)k * 64 + m) * 2);  // AAH[m][k]
        aR += wr * h.x - wi * h.y;
        aI += wi * h.x + wr * h.y;
    }
    aR *= rho; aI *= rho;
#pragma unroll
    for (int s4 = 0; s4 < 4; ++s4) {
        int s = w * 4 + s4;
        aR += Gpart[(size_t)s * 131072 + (size_t)b * 128 + m];
        aI += Gpart[(size_t)s * 131072 + (size_t)b * 128 + 64 + m];
    }
    partA[w][m] = make_float2(aR, aI);
    __syncthreads();
    if (w == 0) {
        float2 p0 = partA[0][m], p1 = partA[1][m], p2 = partA[2][m], p3 = partA[3][m];
        AbS[m] = make_float2(p0.x + p1.x + p2.x + p3.x, p0.y + p1.y + p2.y + p3.y);
    }
    __syncthreads();
    float tR = 0.f, tI = 0.f;
#pragma unroll
    for (int kk = 0; kk < 16; ++kk) {
        int k = w * 16 + kk;
        float2 Wv = *(const float2*)(Wt + ((size_t)k * 64 + m) * 2);   // W[m][k]
        float2 ab = AbS[k];
        tR += ab.x * Wv.x - ab.y * Wv.y;
        tI += ab.y * Wv.x + ab.x * Wv.y;
    }
    partB[w][m] = make_float2(tR, tI);
    __syncthreads();
    if (w == 0) {
        float2 q0 = partB[0][m], q1 = partB[1][m], q2 = partB[2][m], q3 = partB[3][m];
        float sR = q0.x + q1.x + q2.x + q3.x;
        float sI = q0.y + q1.y + q2.y + q3.y;
        qb[(size_t)b * 128 + m] = f2b(rho * wS[m] - sR);
        qb[(size_t)b * 128 + 64 + m] = f2b(rho * wS[64 + m] - sI);
    }
}

// ---------------------------------------------------------------------------
// k_H23: fused x-update + Ax partials; last step also writes fp32 out (real).
__global__ __launch_bounds__(512, 2) void k_H23(const unsigned short* qb, const unsigned short* ATb,
                                                const unsigned short* rnb, const unsigned short* Abf,
                                                float* out, float* Axpart, int last) {
    __shared__ __align__(16) char lds_buf[8 * 8448];
    int t = threadIdx.x;
    int lane = t & 63;
    int w = t >> 6;                               // 0..7
    int l15 = lane & 15;
    int q8 = (lane >> 4) * 8;
    int row = (lane >> 4) * 4;
    int slab = blockIdx.x;
    int b0 = blockIdx.y * 16;
    int n0 = slab * 1024 + w * 128;               // 128 cols per wave
    short* xs = (short*)(lds_buf + w * 8448);     // [16][264] bf16 (cols 0..127 used)
    float* rs = (float*)(lds_buf + w * 8448);     // [16][132] fp32 alias (same wave only)

    // ---- phase 1
    bf16x8 a[4];
    const unsigned short* qrow = qb + (size_t)(b0 + l15) * 128 + q8;
#pragma unroll
    for (int ks = 0; ks < 4; ++ks) a[ks] = *(const bf16x8*)(qrow + ks * 32);
#pragma unroll 2
    for (int nt = 0; nt < 8; ++nt) {
        f32x4 acc = {};
        const unsigned short* bbase = ATb + (size_t)(n0 + nt * 16 + l15) * 128 + q8;
#pragma unroll
        for (int ks = 0; ks < 4; ++ks) {
            bf16x8 bf = *(const bf16x8*)(bbase + ks * 32);
            acc = __builtin_amdgcn_mfma_f32_16x16x32_bf16(a[ks], bf, acc, 0, 0, 0);
        }
        int ncol = n0 + nt * 16 + l15;
        int nloc = nt * 16 + l15;
#pragma unroll
        for (int r = 0; r < 4; ++r) {
            size_t ridx = (size_t)(b0 + row + r) * 16384 + ncol;   // real row of rn/out
            float v = fmaxf(acc[r] + b2f(rnb[ridx]), 0.f);
            if (last) out[ridx] = v;
            xs[(row + r) * 264 + nloc] = (short)f2b(v);
        }
    }
    // ---- phase 2 (wave-private x-stage: lgkmcnt orders RAW)
    f32x4 acc8[8] = {};
#pragma unroll
    for (int ks = 0; ks < 4; ++ks) {
        bf16x8 xf = *(const bf16x8*)(xs + l15 * 264 + ks * 32 + q8);
#pragma unroll
        for (int ot = 0; ot < 8; ++ot) {
            const unsigned short* bp = Abf + (size_t)(ot * 16 + l15) * 8192 + n0 + ks * 32 + q8;
            acc8[ot] = __builtin_amdgcn_mfma_f32_16x16x32_bf16(xf, *(const bf16x8*)bp, acc8[ot], 0, 0, 0);
        }
    }
    // ---- phase 3
    __syncthreads();
#pragma unroll
    for (int ot = 0; ot < 8; ++ot)
#pragma unroll
        for (int r = 0; r < 4; ++r)
            rs[(row + r) * 132 + ot * 16 + l15] = acc8[ot][r];
    __syncthreads();
#pragma unroll
    for (int e = t; e < 2048; e += 512) {
        int b = e >> 7, o = e & 127;
        float sAx = 0.f;
#pragma unroll
        for (int ww = 0; ww < 8; ++ww)
            sAx += ((const float*)(lds_buf + ww * 8448))[b * 132 + o];
        Axpart[(size_t)slab * 131072 + (size_t)(b0 + b) * 128 + o] = sAx;
    }
}

// ---------------------------------------------------------------------------
// final epilogue: uout only (z/u dead after last step)
__global__ __launch_bounds__(128) void k_small3f(const float* Axpart, const float* uprev,
                                                 const float* y, const float* le,
                                                 float* uout) {
    __shared__ float red[2];
    int b = blockIdx.x, t = threadIdx.x;
    size_t idx = (size_t)b * 128 + t;
    float ax = 0.f;
#pragma unroll
    for (int s = 0; s < NS3; ++s) ax += Axpart[(size_t)s * 131072 + idx];
    float uo = uprev[idx], yv = y[idx];
    float v = ax + uo - yv;
    float sq = v * v;
    for (int off = 32; off > 0; off >>= 1) sq += __shfl_down(sq, off, 64);
    if ((t & 63) == 0) red[t >> 6] = sq;
    __syncthreads();
    float tot = red[0] + red[1];
    float eps = expf(le[0]);
    float scale = fminf(1.f, eps / (sqrtf(tot) + 1e-12f));
    float zv = yv + v * scale;
    float un = uo + ax - zv;
    uout[idx] = un;
}

// ---------------------------------------------------------------------------
extern "C" void kernel_launch(void* const* d_in, const int* in_sizes, int n_in,
                              void* d_out, int out_size, void* d_ws, size_t ws_size,
                              hipStream_t stream) {
    const float* rn  = (const float*)d_in[0];   // (B,2,N)
    const float* y   = (const float*)d_in[1];   // (B,2,M)
    const float* uin = (const float*)d_in[2];   // (B,2,M)
    const float* A   = (const float*)d_in[3];   // (2,M,N)
    const float* lr  = (const float*)d_in[4];   // log_rho
    const float* le  = (const float*)d_in[5];   // log_epsilon

    float* out = (float*)d_out;
    float* ws  = (float*)d_ws;

    float* Gpart  = ws;                             // 16*131072 = 2,097,152 f
    float* Axpart = Gpart + (size_t)NSG * 131072;   //  8*131072 = 1,048,576 f
    float* S      = Axpart + (size_t)NS3 * 131072;  // 8192
    float* AAHT   = S + 8192;                       // 8192
    float* Wt     = AAHT + 8192;                    // 8192
    float* z      = Wt + 8192;                      // 131072 (unused since r8 fusion)
    float* u      = z + 131072;                     // 131072
    unsigned short* qb  = (unsigned short*)(u + 131072);  // 131,072 us
    unsigned short* rnb = qb + 131072;              // B*2*N  = 16,777,216 us
    unsigned short* WgT = rnb + (size_t)B_ * 16384; // 128*16384 = 2,097,152 us
    unsigned short* Abf = WgT + 2097152;            // 2*64*8192 = 1,048,576 us
    unsigned short* ATb = Abf + 1048576;            // 8192*128  = 1,048,576 us
    float* uout = out + (size_t)B_ * 2 * N_;

    k_prep<<<2176, 256, 0, stream>>>(A, Abf, WgT, ATb, out);   // 128 prep + 2048 imag-zero
    k_cvt<<<8192, 256, 0, stream>>>(rn, rnb);
    k_Sbuild<<<2080, 256, 0, stream>>>(A, lr, S, AAHT);
    k_Ginv<<<512, 256, 0, stream>>>(rnb, WgT, Gpart, S, Wt);

    // step 0
    k_F<<<B_, 256, 0, stream>>>(Gpart, AAHT, Wt, Axpart, y, uin, u, lr, le, qb, 0);
    k_H23<<<dim3(NS3, 64), 512, 0, stream>>>(qb, ATb, rnb, Abf, out, Axpart, 0);
    // step 1 (fused s3_0 + s12_1)
    k_F<<<B_, 256, 0, stream>>>(Gpart, AAHT, Wt, Axpart, y, uin, u, lr, le, qb, 1);
    k_H23<<<dim3(NS3, 64), 512, 0, stream>>>(qb, ATb, rnb, Abf, out, Axpart, 0);
    // step 2 (fused s3_1 + s12_2)
    k_F<<<B_, 256, 0, stream>>>(Gpart, AAHT, Wt, Axpart, y, u, u, lr, le, qb, 1);
    k_H23<<<dim3(NS3, 64), 512, 0, stream>>>(qb, ATb, rnb, Abf, out, Axpart, 1);
    // final epilogue (s3_2): uout only
    k_small3f<<<B_, 128, 0, stream>>>(Axpart, u, y, le, uout);
}